// Round 2
// baseline (435.558 us; speedup 1.0000x reference)
//
#include <hip/hip_runtime.h>
#include <hip/hip_bf16.h>

typedef __attribute__((ext_vector_type(8))) short short8;
typedef __attribute__((ext_vector_type(4))) short short4b;
typedef __attribute__((ext_vector_type(4))) float f32x4;

static constexpr int Bb = 2, Tt = 2048, Cc = 1024, Hh = 16;
static constexpr int BT = Bb * Tt;     // 4096
static constexpr int N1 = 3 * Cc;      // 3072

__device__ __forceinline__ unsigned short f2b(float f) {
  union { float f; unsigned u; } v; v.f = f;
  unsigned r = v.u + 0x7fffu + ((v.u >> 16) & 1u);
  return (unsigned short)(r >> 16);
}
__device__ __forceinline__ float b2f(short s) {
  union { unsigned u; float f; } v; v.u = ((unsigned)(unsigned short)s) << 16;
  return v.f;
}

#if defined(__has_builtin)
#if __has_builtin(__builtin_amdgcn_mfma_f32_16x16x16bf16_1k)
#define HAVE_MFMA16 1
#endif
#endif

// PV micro-op: O^T_tile += A(V^T 16x16) * B(P^T 16x16), contraction K=16.
__device__ __forceinline__ f32x4 pv_mfma(short4b vf, short4b pf, f32x4 c) {
#if HAVE_MFMA16
  return __builtin_amdgcn_mfma_f32_16x16x16bf16_1k(vf, pf, c, 0, 0, 0);
#else
  // zero-padded K=32 MFMA: slots 4..7 of both operands are zero, so they
  // contribute nothing; slots 0..3 use the same (lane,slot)->k convention
  // on both A and B, so the contraction is exact.
  short8 a = {vf[0], vf[1], vf[2], vf[3], (short)0, (short)0, (short)0, (short)0};
  short8 b = {pf[0], pf[1], pf[2], pf[3], (short)0, (short)0, (short)0, (short)0};
  return __builtin_amdgcn_mfma_f32_16x16x32_bf16(a, b, c, 0, 0, 0);
#endif
}

// ---------------- cast f32 -> bf16, 8 elems/thread ----------------
__global__ __launch_bounds__(256) void k_cast(const float* __restrict__ in,
                                              unsigned short* __restrict__ out, int n) {
  int i = (blockIdx.x * 256 + threadIdx.x) * 8;
  if (i >= n) return;
  float4 a = *reinterpret_cast<const float4*>(in + i);
  float4 b = *reinterpret_cast<const float4*>(in + i + 4);
  short8 o;
  o[0] = f2b(a.x); o[1] = f2b(a.y); o[2] = f2b(a.z); o[3] = f2b(a.w);
  o[4] = f2b(b.x); o[5] = f2b(b.y); o[6] = f2b(b.z); o[7] = f2b(b.w);
  *reinterpret_cast<short8*>(out + i) = o;
}

// ------------- transpose + cast: in R x Ccol f32 -> out Ccol x R bf16 -------------
__global__ __launch_bounds__(256) void k_tcast(const float* __restrict__ in,
                                               unsigned short* __restrict__ out,
                                               int R, int Ccol) {
  __shared__ float tile[32][33];
  int cb = blockIdx.x * 32, rb = blockIdx.y * 32;
  int tx = threadIdx.x & 31, ty = threadIdx.x >> 5;  // ty 0..7
  for (int i = 0; i < 32; i += 8)
    tile[ty + i][tx] = in[(size_t)(rb + ty + i) * Ccol + cb + tx];
  __syncthreads();
  for (int i = 0; i < 32; i += 8)
    out[(size_t)(cb + ty + i) * R + rb + tx] = f2b(tile[tx][ty + i]);
}

// ---------------- bf16 GEMM: C(MxN) = A(MxK) * Bt(NxK)^T + bias ----------------
template <int OUT_BF16>
__global__ __launch_bounds__(256)
void k_gemm(const unsigned short* __restrict__ A, const unsigned short* __restrict__ Bt,
            const float* __restrict__ bias, void* __restrict__ Cout,
            int M, int N, int K) {
  __shared__ unsigned short Al[128 * 64];
  __shared__ unsigned short Bl[128 * 64];
  const int tid = threadIdx.x;
  const int lane = tid & 63;
  const int w = tid >> 6;
  const int wm = w >> 1, wn = w & 1;
  const int mb = blockIdx.y, nb = blockIdx.x;
  const int l15 = lane & 15, l4 = lane >> 4;
  f32x4 acc[4][4] = {};

  const size_t arow0 = (size_t)mb * 128;
  const size_t brow0 = (size_t)nb * 128;

  for (int k0 = 0; k0 < K; k0 += 64) {
    __syncthreads();
#pragma unroll
    for (int cc = 0; cc < 4; cc++) {
      int c = w + cc * 4;                 // wave-uniform chunk id 0..15
      int e = c * 512 + lane * 8;         // bf16 element offset in 128x64 tile
      int row = e >> 6, col = e & 63;
      const unsigned short* ga = A + (arow0 + row) * (size_t)K + k0 + col;
      const unsigned short* gb = Bt + (brow0 + row) * (size_t)K + k0 + col;
      __builtin_amdgcn_global_load_lds((__attribute__((address_space(1))) void*)ga,
                                       (__attribute__((address_space(3))) void*)(Al + c * 512),
                                       16, 0, 0);
      __builtin_amdgcn_global_load_lds((__attribute__((address_space(1))) void*)gb,
                                       (__attribute__((address_space(3))) void*)(Bl + c * 512),
                                       16, 0, 0);
    }
    __syncthreads();
#pragma unroll
    for (int kc = 0; kc < 2; kc++) {
      short8 af[4], bfr[4];
#pragma unroll
      for (int m = 0; m < 4; m++)
        af[m] = *reinterpret_cast<const short8*>(&Al[(wm * 64 + m * 16 + l15) * 64 + kc * 32 + l4 * 8]);
#pragma unroll
      for (int n = 0; n < 4; n++)
        bfr[n] = *reinterpret_cast<const short8*>(&Bl[(wn * 64 + n * 16 + l15) * 64 + kc * 32 + l4 * 8]);
#pragma unroll
      for (int m = 0; m < 4; m++)
#pragma unroll
        for (int n = 0; n < 4; n++)
          acc[m][n] = __builtin_amdgcn_mfma_f32_16x16x32_bf16(af[m], bfr[n], acc[m][n], 0, 0, 0);
    }
  }

#pragma unroll
  for (int m = 0; m < 4; m++) {
#pragma unroll
    for (int n = 0; n < 4; n++) {
      int ccol = nb * 128 + wn * 64 + n * 16 + l15;
      float bv = bias ? bias[ccol] : 0.f;
#pragma unroll
      for (int j = 0; j < 4; j++) {
        int r = mb * 128 + wm * 64 + m * 16 + l4 * 4 + j;
        float v = acc[m][n][j] + bv;
        if (OUT_BF16)
          ((unsigned short*)Cout)[(size_t)r * N + ccol] = f2b(v);
        else
          ((float*)Cout)[(size_t)r * N + ccol] = v;
      }
    }
  }
}

// ---------------- RoPE + head relayout + V transpose ----------------
__global__ __launch_bounds__(256)
void k_rope(const unsigned short* __restrict__ qkv, const float* __restrict__ rope,
            unsigned short* __restrict__ Qs, unsigned short* __restrict__ Ks,
            unsigned short* __restrict__ Vt) {
  __shared__ unsigned short vt_l[64][72];  // 16B-aligned rows (144B stride)
  int bid = blockIdx.x;
  int tb = bid & 31, h = (bid >> 5) & 15, b = bid >> 9;
  int tid = threadIdx.x;
#pragma unroll
  for (int r = 0; r < 2; r++) {
    int e = (r * 256 + tid) * 8;
    int tl = e >> 6, d = e & 63;
    int t = tb * 64 + tl;
    const unsigned short* rowp = qkv + (size_t)(b * Tt + t) * 3072 + h * 64 + d;
    short8 qv = *reinterpret_cast<const short8*>(rowp);
    short8 kv = *reinterpret_cast<const short8*>(rowp + 1024);
    short8 vv = *reinterpret_cast<const short8*>(rowp + 2048);
    short8 qo, ko;
#pragma unroll
    for (int p = 0; p < 4; p++) {
      int j = (d >> 1) + p;
      float4 rv = *reinterpret_cast<const float4*>(rope + ((size_t)t * 32 + j) * 4);
      // rv = (cos, -sin, sin, cos)
      float xq = b2f(qv[2 * p]), yq = b2f(qv[2 * p + 1]);
      float xk = b2f(kv[2 * p]), yk = b2f(kv[2 * p + 1]);
      qo[2 * p]     = (short)f2b((xq * rv.x + yq * rv.y) * 0.125f);
      qo[2 * p + 1] = (short)f2b((xq * rv.z + yq * rv.w) * 0.125f);
      ko[2 * p]     = (short)f2b(xk * rv.x + yk * rv.y);
      ko[2 * p + 1] = (short)f2b(xk * rv.z + yk * rv.w);
    }
    size_t qdst = ((size_t)(b * 16 + h) * Tt + t) * 64 + d;
    *reinterpret_cast<short8*>(Qs + qdst) = qo;
    *reinterpret_cast<short8*>(Ks + qdst) = ko;
#pragma unroll
    for (int i2 = 0; i2 < 8; i2++) vt_l[d + i2][tl] = (unsigned short)vv[i2];
  }
  __syncthreads();
#pragma unroll
  for (int r = 0; r < 2; r++) {
    int e = (r * 256 + tid) * 8;
    int dl = e >> 6, tl = e & 63;
    short8 o = *reinterpret_cast<const short8*>(&vt_l[dl][tl]);
    *reinterpret_cast<short8*>(Vt + ((size_t)(b * 16 + h) * 64 + dl) * Tt + tb * 64 + tl) = o;
  }
}

// ---------------- causal flash attention (swapped-operand, reg-resident P) -------
// Per wave: 16 q-rows (q = lane&15 for BOTH S^T and O^T), KV step 64.
// S^T tile: mfma(K_frag, Q_frag) -> lane holds S[k=16*t2+4*l4+j][q=l15].
// Softmax: lane-local regs + 2 shfl_xor levels (across l4 quads).
// PV: O^T += V^T * P^T via K=16 MFMA; lane's 4 P values ARE the B-fragment.
template <bool DIAG>
__device__ __forceinline__ void attn_tile(
    const unsigned short* __restrict__ Kb, const unsigned short* __restrict__ Vb,
    int kv0, int w, int l15, int l4, short8 q0, short8 q1,
    float& m_run, float& l_run, f32x4 oacc[4]) {
  const int tmax = DIAG ? w : 3;
  f32x4 st[4];
#pragma unroll
  for (int t2 = 0; t2 < 4; t2++) {
    if (!DIAG || t2 <= tmax) {
      const unsigned short* kp = Kb + (size_t)(kv0 + t2 * 16 + l15) * 64;
      short8 kf0 = *reinterpret_cast<const short8*>(kp + l4 * 8);
      short8 kf1 = *reinterpret_cast<const short8*>(kp + 32 + l4 * 8);
      f32x4 s = {};
      s = __builtin_amdgcn_mfma_f32_16x16x32_bf16(kf0, q0, s, 0, 0, 0);
      s = __builtin_amdgcn_mfma_f32_16x16x32_bf16(kf1, q1, s, 0, 0, 0);
      if (DIAG && t2 == tmax) {
#pragma unroll
        for (int j = 0; j < 4; j++)
          if (4 * l4 + j > l15) s[j] = -1e30f;   // k = qw0+4*l4+j vs q = qw0+l15
      }
      st[t2] = s;
    } else {
      st[t2] = f32x4{-1e30f, -1e30f, -1e30f, -1e30f};
    }
  }
  // row max over the 16 lane-local scores, then across the 4 lane-quads
  float r0 = fmaxf(fmaxf(st[0][0], st[0][1]), fmaxf(st[0][2], st[0][3]));
  float r1 = fmaxf(fmaxf(st[1][0], st[1][1]), fmaxf(st[1][2], st[1][3]));
  float r2 = fmaxf(fmaxf(st[2][0], st[2][1]), fmaxf(st[2][2], st[2][3]));
  float r3 = fmaxf(fmaxf(st[3][0], st[3][1]), fmaxf(st[3][2], st[3][3]));
  float mx = fmaxf(fmaxf(r0, r1), fmaxf(r2, r3));
  mx = fmaxf(mx, __shfl_xor(mx, 16));
  mx = fmaxf(mx, __shfl_xor(mx, 32));
  float nm = fmaxf(m_run, mx);
  float fsc = __expf(m_run - nm);
  m_run = nm;

  short4b pvs[4];
  float ps[4];
#pragma unroll
  for (int t2 = 0; t2 < 4; t2++) {
    float p0 = __expf(st[t2][0] - nm);
    float p1 = __expf(st[t2][1] - nm);
    float p2 = __expf(st[t2][2] - nm);
    float p3 = __expf(st[t2][3] - nm);
    ps[t2] = (p0 + p1) + (p2 + p3);
    pvs[t2][0] = (short)((__builtin_bit_cast(unsigned, p0) + 0x8000u) >> 16);
    pvs[t2][1] = (short)((__builtin_bit_cast(unsigned, p1) + 0x8000u) >> 16);
    pvs[t2][2] = (short)((__builtin_bit_cast(unsigned, p2) + 0x8000u) >> 16);
    pvs[t2][3] = (short)((__builtin_bit_cast(unsigned, p3) + 0x8000u) >> 16);
  }
  float psum = (ps[0] + ps[1]) + (ps[2] + ps[3]);
  psum += __shfl_xor(psum, 16);
  psum += __shfl_xor(psum, 32);
  l_run = l_run * fsc + psum;
#pragma unroll
  for (int n = 0; n < 4; n++)
#pragma unroll
    for (int j = 0; j < 4; j++) oacc[n][j] *= fsc;
#pragma unroll
  for (int t2 = 0; t2 < 4; t2++) {
    if (!DIAG || t2 <= tmax) {
#pragma unroll
      for (int n = 0; n < 4; n++) {
        short4b vf = *reinterpret_cast<const short4b*>(
            Vb + (size_t)(n * 16 + l15) * Tt + kv0 + t2 * 16 + l4 * 4);
        oacc[n] = pv_mfma(vf, pvs[t2], oacc[n]);
      }
    }
  }
}

__global__ __launch_bounds__(256)
void k_attn(const unsigned short* __restrict__ Qs, const unsigned short* __restrict__ Ks,
            const unsigned short* __restrict__ Vt, unsigned short* __restrict__ Y) {
  int tid = threadIdx.x, lane = tid & 63, w = tid >> 6;
  int bid = blockIdx.x;
  int bh = bid >> 5, qb = bid & 31;
  int b = bh >> 4, h = bh & 15;
  int l15 = lane & 15, l4 = lane >> 4;
  int qw0 = qb * 64 + w * 16;
  const unsigned short* Qb = Qs + (size_t)bh * Tt * 64;
  const unsigned short* Kb = Ks + (size_t)bh * Tt * 64;
  const unsigned short* Vb = Vt + (size_t)bh * 64 * Tt;

  short8 q0 = *reinterpret_cast<const short8*>(Qb + (size_t)(qw0 + l15) * 64 + l4 * 8);
  short8 q1 = *reinterpret_cast<const short8*>(Qb + (size_t)(qw0 + l15) * 64 + 32 + l4 * 8);

  float m_run = -1e30f, l_run = 0.f;
  f32x4 oacc[4] = {};

  const int diag0 = qb * 64;
  for (int kv0 = 0; kv0 < diag0; kv0 += 64)
    attn_tile<false>(Kb, Vb, kv0, w, l15, l4, q0, q1, m_run, l_run, oacc);
  attn_tile<true>(Kb, Vb, diag0, w, l15, l4, q0, q1, m_run, l_run, oacc);

  float inv = 1.0f / l_run;
  int t = qw0 + l15;
#pragma unroll
  for (int n = 0; n < 4; n++) {
    short4b o;
#pragma unroll
    for (int j = 0; j < 4; j++) o[j] = (short)f2b(oacc[n][j] * inv);
    *reinterpret_cast<short4b*>(
        &Y[((size_t)b * Tt + t) * Cc + h * 64 + n * 16 + l4 * 4]) = o;
  }
}

extern "C" void kernel_launch(void* const* d_in, const int* in_sizes, int n_in,
                              void* d_out, int out_size, void* d_ws, size_t ws_size,
                              hipStream_t stream) {
  (void)in_sizes; (void)n_in; (void)out_size; (void)ws_size;
  const float* x      = (const float*)d_in[0];
  const float* W_attn = (const float*)d_in[1];
  const float* b_attn = (const float*)d_in[2];
  const float* W_proj = (const float*)d_in[3];
  const float* b_proj = (const float*)d_in[4];
  const float* rope   = (const float*)d_in[5];
  float* out = (float*)d_out;

  char* ws = (char*)d_ws;
  unsigned short* xb  = (unsigned short*)(ws);                     // 8 MB
  unsigned short* WaT = (unsigned short*)(ws + (8u << 20));        // 6 MB
  unsigned short* WpT = (unsigned short*)(ws + (14u << 20));       // 2 MB
  unsigned short* qkv = (unsigned short*)(ws + (16u << 20));       // 24 MB
  unsigned short* Qs  = (unsigned short*)(ws + (40u << 20));       // 8 MB
  unsigned short* Ks  = (unsigned short*)(ws + (48u << 20));       // 8 MB
  unsigned short* Vt  = (unsigned short*)(ws + (56u << 20));       // 8 MB
  unsigned short* Yb  = (unsigned short*)(ws + (64u << 20));       // 8 MB  (total 72 MB)

  k_cast<<<2048, 256, 0, stream>>>(x, xb, BT * Cc);
  k_tcast<<<dim3(N1 / 32, Cc / 32), 256, 0, stream>>>(W_attn, WaT, Cc, N1);
  k_tcast<<<dim3(Cc / 32, Cc / 32), 256, 0, stream>>>(W_proj, WpT, Cc, Cc);
  k_gemm<1><<<dim3(N1 / 128, BT / 128), 256, 0, stream>>>(xb, WaT, b_attn, qkv, BT, N1, Cc);
  k_rope<<<Bb * Hh * (Tt / 64), 256, 0, stream>>>(qkv, rope, Qs, Ks, Vt);
  k_attn<<<Bb * Hh * (Tt / 64), 256, 0, stream>>>(Qs, Ks, Vt, Yb);
  k_gemm<0><<<dim3(Cc / 128, BT / 128), 256, 0, stream>>>(Yb, WpT, b_proj, out, BT, Cc, Cc);
}

// Round 3
// 171.306 us; speedup vs baseline: 2.5426x; 2.5426x over previous
//
#include <hip/hip_runtime.h>
#include <hip/hip_bf16.h>

typedef __attribute__((ext_vector_type(8))) short short8;
typedef __attribute__((ext_vector_type(4))) short short4b;
typedef __attribute__((ext_vector_type(4))) float f32x4;

static constexpr int Bb = 2, Tt = 2048, Cc = 1024, Hh = 16;
static constexpr int BT = Bb * Tt;     // 4096
static constexpr int N1 = 3 * Cc;      // 3072

__device__ __forceinline__ unsigned short f2b(float f) {
  union { float f; unsigned u; } v; v.f = f;
  unsigned r = v.u + 0x7fffu + ((v.u >> 16) & 1u);
  return (unsigned short)(r >> 16);
}
__device__ __forceinline__ float b2f(short s) {
  union { unsigned u; float f; } v; v.u = ((unsigned)(unsigned short)s) << 16;
  return v.f;
}

#if defined(__has_builtin)
#if __has_builtin(__builtin_amdgcn_mfma_f32_16x16x16bf16_1k)
#define HAVE_MFMA16 1
#endif
#endif

// PV micro-op: O^T_tile += A(V^T 16x16) * B(P^T 16x16), contraction K=16.
__device__ __forceinline__ f32x4 pv_mfma(short4b vf, short4b pf, f32x4 c) {
#if HAVE_MFMA16
  return __builtin_amdgcn_mfma_f32_16x16x16bf16_1k(vf, pf, c, 0, 0, 0);
#else
  short8 a = {vf[0], vf[1], vf[2], vf[3], (short)0, (short)0, (short)0, (short)0};
  short8 b = {pf[0], pf[1], pf[2], pf[3], (short)0, (short)0, (short)0, (short)0};
  return __builtin_amdgcn_mfma_f32_16x16x32_bf16(a, b, c, 0, 0, 0);
#endif
}

// ---------------- cast f32 -> bf16, 8 elems/thread ----------------
__global__ __launch_bounds__(256) void k_cast(const float* __restrict__ in,
                                              unsigned short* __restrict__ out, int n) {
  int i = (blockIdx.x * 256 + threadIdx.x) * 8;
  if (i >= n) return;
  float4 a = *reinterpret_cast<const float4*>(in + i);
  float4 b = *reinterpret_cast<const float4*>(in + i + 4);
  short8 o;
  o[0] = f2b(a.x); o[1] = f2b(a.y); o[2] = f2b(a.z); o[3] = f2b(a.w);
  o[4] = f2b(b.x); o[5] = f2b(b.y); o[6] = f2b(b.z); o[7] = f2b(b.w);
  *reinterpret_cast<short8*>(out + i) = o;
}

// ------------- transpose + cast: in R x Ccol f32 -> out Ccol x R bf16 -------------
__global__ __launch_bounds__(256) void k_tcast(const float* __restrict__ in,
                                               unsigned short* __restrict__ out,
                                               int R, int Ccol) {
  __shared__ float tile[32][33];
  int cb = blockIdx.x * 32, rb = blockIdx.y * 32;
  int tx = threadIdx.x & 31, ty = threadIdx.x >> 5;  // ty 0..7
  for (int i = 0; i < 32; i += 8)
    tile[ty + i][tx] = in[(size_t)(rb + ty + i) * Ccol + cb + tx];
  __syncthreads();
  for (int i = 0; i < 32; i += 8)
    out[(size_t)(cb + ty + i) * R + rb + tx] = f2b(tile[tx][ty + i]);
}

// ---------------- bf16 GEMM: C(MxN) = A(MxK) * Bt(NxK)^T + bias ----------------
template <int OUT_BF16>
__global__ __launch_bounds__(256)
void k_gemm(const unsigned short* __restrict__ A, const unsigned short* __restrict__ Bt,
            const float* __restrict__ bias, void* __restrict__ Cout,
            int M, int N, int K) {
  __shared__ unsigned short Al[128 * 64];
  __shared__ unsigned short Bl[128 * 64];
  const int tid = threadIdx.x;
  const int lane = tid & 63;
  const int w = tid >> 6;
  const int wm = w >> 1, wn = w & 1;
  const int mb = blockIdx.y, nb = blockIdx.x;
  const int l15 = lane & 15, l4 = lane >> 4;
  f32x4 acc[4][4] = {};

  const size_t arow0 = (size_t)mb * 128;
  const size_t brow0 = (size_t)nb * 128;

  for (int k0 = 0; k0 < K; k0 += 64) {
    __syncthreads();
#pragma unroll
    for (int cc = 0; cc < 4; cc++) {
      int c = w + cc * 4;                 // wave-uniform chunk id 0..15
      int e = c * 512 + lane * 8;         // bf16 element offset in 128x64 tile
      int row = e >> 6, col = e & 63;
      const unsigned short* ga = A + (arow0 + row) * (size_t)K + k0 + col;
      const unsigned short* gb = Bt + (brow0 + row) * (size_t)K + k0 + col;
      __builtin_amdgcn_global_load_lds((__attribute__((address_space(1))) void*)ga,
                                       (__attribute__((address_space(3))) void*)(Al + c * 512),
                                       16, 0, 0);
      __builtin_amdgcn_global_load_lds((__attribute__((address_space(1))) void*)gb,
                                       (__attribute__((address_space(3))) void*)(Bl + c * 512),
                                       16, 0, 0);
    }
    __syncthreads();
#pragma unroll
    for (int kc = 0; kc < 2; kc++) {
      short8 af[4], bfr[4];
#pragma unroll
      for (int m = 0; m < 4; m++)
        af[m] = *reinterpret_cast<const short8*>(&Al[(wm * 64 + m * 16 + l15) * 64 + kc * 32 + l4 * 8]);
#pragma unroll
      for (int n = 0; n < 4; n++)
        bfr[n] = *reinterpret_cast<const short8*>(&Bl[(wn * 64 + n * 16 + l15) * 64 + kc * 32 + l4 * 8]);
#pragma unroll
      for (int m = 0; m < 4; m++)
#pragma unroll
        for (int n = 0; n < 4; n++)
          acc[m][n] = __builtin_amdgcn_mfma_f32_16x16x32_bf16(af[m], bfr[n], acc[m][n], 0, 0, 0);
    }
  }

#pragma unroll
  for (int m = 0; m < 4; m++) {
#pragma unroll
    for (int n = 0; n < 4; n++) {
      int ccol = nb * 128 + wn * 64 + n * 16 + l15;
      float bv = bias ? bias[ccol] : 0.f;
#pragma unroll
      for (int j = 0; j < 4; j++) {
        int r = mb * 128 + wm * 64 + m * 16 + l4 * 4 + j;
        float v = acc[m][n][j] + bv;
        if (OUT_BF16)
          ((unsigned short*)Cout)[(size_t)r * N + ccol] = f2b(v);
        else
          ((float*)Cout)[(size_t)r * N + ccol] = v;
      }
    }
  }
}

// ---------------- RoPE + head relayout + V transpose ----------------
__global__ __launch_bounds__(256)
void k_rope(const unsigned short* __restrict__ qkv, const float* __restrict__ rope,
            unsigned short* __restrict__ Qs, unsigned short* __restrict__ Ks,
            unsigned short* __restrict__ Vt) {
  __shared__ unsigned short vt_l[64][72];  // 16B-aligned rows (144B stride)
  int bid = blockIdx.x;
  int tb = bid & 31, h = (bid >> 5) & 15, b = bid >> 9;
  int tid = threadIdx.x;
#pragma unroll
  for (int r = 0; r < 2; r++) {
    int e = (r * 256 + tid) * 8;
    int tl = e >> 6, d = e & 63;
    int t = tb * 64 + tl;
    const unsigned short* rowp = qkv + (size_t)(b * Tt + t) * 3072 + h * 64 + d;
    short8 qv = *reinterpret_cast<const short8*>(rowp);
    short8 kv = *reinterpret_cast<const short8*>(rowp + 1024);
    short8 vv = *reinterpret_cast<const short8*>(rowp + 2048);
    short8 qo, ko;
#pragma unroll
    for (int p = 0; p < 4; p++) {
      int j = (d >> 1) + p;
      float4 rv = *reinterpret_cast<const float4*>(rope + ((size_t)t * 32 + j) * 4);
      // rv = (cos, -sin, sin, cos)
      float xq = b2f(qv[2 * p]), yq = b2f(qv[2 * p + 1]);
      float xk = b2f(kv[2 * p]), yk = b2f(kv[2 * p + 1]);
      qo[2 * p]     = (short)f2b((xq * rv.x + yq * rv.y) * 0.125f);
      qo[2 * p + 1] = (short)f2b((xq * rv.z + yq * rv.w) * 0.125f);
      ko[2 * p]     = (short)f2b(xk * rv.x + yk * rv.y);
      ko[2 * p + 1] = (short)f2b(xk * rv.z + yk * rv.w);
    }
    size_t qdst = ((size_t)(b * 16 + h) * Tt + t) * 64 + d;
    *reinterpret_cast<short8*>(Qs + qdst) = qo;
    *reinterpret_cast<short8*>(Ks + qdst) = ko;
#pragma unroll
    for (int i2 = 0; i2 < 8; i2++) vt_l[d + i2][tl] = (unsigned short)vv[i2];
  }
  __syncthreads();
#pragma unroll
  for (int r = 0; r < 2; r++) {
    int e = (r * 256 + tid) * 8;
    int dl = e >> 6, tl = e & 63;
    short8 o = *reinterpret_cast<const short8*>(&vt_l[dl][tl]);
    *reinterpret_cast<short8*>(Vt + ((size_t)(b * 16 + h) * 64 + dl) * Tt + tb * 64 + tl) = o;
  }
}

// ---------------- causal flash attention (LDS-staged, 2-phase, swizzled) ---------
// Per wave: 16 q-rows (q = lane&15 for BOTH S^T and O^T), KV tile 64.
// K,V tiles staged block-wide into LDS via global_load_lds with pre-swizzled
// global source (colb ^ ((row&7)<<4), 16B units); same XOR on ds_read side.
template <bool DIAG>
__device__ __forceinline__ void attn_tile_lds(
    const unsigned short* Kl, const unsigned short* Vl,
    int w, int l15, int l4, short8 q0, short8 q1,
    float& m_run, float& l_run, f32x4 oacc[4]) {
  const int tmax = DIAG ? w : 3;
  f32x4 st[4];
#pragma unroll
  for (int t2 = 0; t2 < 4; t2++) {
    if (!DIAG || t2 <= tmax) {
      int r = t2 * 16 + l15;
      int sw = (r & 7) << 4;
      const unsigned short* kp = Kl + r * 64;
      short8 kf0 = *reinterpret_cast<const short8*>(kp + (((l4 * 16) ^ sw) >> 1));
      short8 kf1 = *reinterpret_cast<const short8*>(kp + (((64 + l4 * 16) ^ sw) >> 1));
      f32x4 s = {};
      s = __builtin_amdgcn_mfma_f32_16x16x32_bf16(kf0, q0, s, 0, 0, 0);
      s = __builtin_amdgcn_mfma_f32_16x16x32_bf16(kf1, q1, s, 0, 0, 0);
      if (DIAG && t2 == tmax) {
#pragma unroll
        for (int j = 0; j < 4; j++)
          if (4 * l4 + j > l15) s[j] = -1e30f;   // k = qw0+4*l4+j vs q = qw0+l15
      }
      st[t2] = s;
    } else {
      st[t2] = f32x4{-1e30f, -1e30f, -1e30f, -1e30f};
    }
  }
  float r0 = fmaxf(fmaxf(st[0][0], st[0][1]), fmaxf(st[0][2], st[0][3]));
  float r1 = fmaxf(fmaxf(st[1][0], st[1][1]), fmaxf(st[1][2], st[1][3]));
  float r2 = fmaxf(fmaxf(st[2][0], st[2][1]), fmaxf(st[2][2], st[2][3]));
  float r3 = fmaxf(fmaxf(st[3][0], st[3][1]), fmaxf(st[3][2], st[3][3]));
  float mx = fmaxf(fmaxf(r0, r1), fmaxf(r2, r3));
  mx = fmaxf(mx, __shfl_xor(mx, 16));
  mx = fmaxf(mx, __shfl_xor(mx, 32));
  float nm = fmaxf(m_run, mx);
  float fsc = __expf(m_run - nm);
  m_run = nm;

  short4b pvs[4];
  float ps[4];
#pragma unroll
  for (int t2 = 0; t2 < 4; t2++) {
    float p0 = __expf(st[t2][0] - nm);
    float p1 = __expf(st[t2][1] - nm);
    float p2 = __expf(st[t2][2] - nm);
    float p3 = __expf(st[t2][3] - nm);
    ps[t2] = (p0 + p1) + (p2 + p3);
    pvs[t2][0] = (short)((__builtin_bit_cast(unsigned, p0) + 0x8000u) >> 16);
    pvs[t2][1] = (short)((__builtin_bit_cast(unsigned, p1) + 0x8000u) >> 16);
    pvs[t2][2] = (short)((__builtin_bit_cast(unsigned, p2) + 0x8000u) >> 16);
    pvs[t2][3] = (short)((__builtin_bit_cast(unsigned, p3) + 0x8000u) >> 16);
  }
  float psum = (ps[0] + ps[1]) + (ps[2] + ps[3]);
  psum += __shfl_xor(psum, 16);
  psum += __shfl_xor(psum, 32);
  l_run = l_run * fsc + psum;
#pragma unroll
  for (int n = 0; n < 4; n++)
#pragma unroll
    for (int j = 0; j < 4; j++) oacc[n][j] *= fsc;
#pragma unroll
  for (int t2 = 0; t2 < 4; t2++) {
    if (!DIAG || t2 <= tmax) {
#pragma unroll
      for (int n = 0; n < 4; n++) {
        int d = n * 16 + l15;
        int colb = (t2 * 32 + l4 * 8) ^ ((d & 7) << 4);
        short4b vf = *reinterpret_cast<const short4b*>(Vl + d * 64 + (colb >> 1));
        oacc[n] = pv_mfma(vf, pvs[t2], oacc[n]);
      }
    }
  }
}

__global__ __launch_bounds__(256)
void k_attn(const unsigned short* __restrict__ Qs, const unsigned short* __restrict__ Ks,
            const unsigned short* __restrict__ Vt, unsigned short* __restrict__ Y) {
  __shared__ unsigned short lds[16384];  // K0|K1 (8192) + V0|V1 (8192), shorts
  int tid = threadIdx.x, lane = tid & 63, w = tid >> 6;
  int bid = blockIdx.x;
  bid = (bid & 7) * 128 + (bid >> 3);    // XCD swizzle: 1024 blocks, 8 XCDs
  int bh = bid >> 5, qb = bid & 31;
  int b = bh >> 4, h = bh & 15;
  int l15 = lane & 15, l4 = lane >> 4;
  int qw0 = qb * 64 + w * 16;
  const unsigned short* Qb = Qs + (size_t)bh * Tt * 64;
  const unsigned short* Kb = Ks + (size_t)bh * Tt * 64;
  const unsigned short* Vb = Vt + (size_t)bh * 64 * Tt;

  // stage one 64-key tile: K rows [kv0,kv0+64) x 64d, V^T rows d x keys.
  // LDS dest is linear (wave-uniform base + lane*16); global source column is
  // pre-swizzled so that LDS[row][col ^ ((row&7)<<4)] = data[row][col].
  auto stage = [&](int bufb, int kv0) {
    int row = (lane >> 3);               // +c*8 below
    int colb = ((lane & 7) * 16) ^ (((lane >> 3) & 7) << 4);
#pragma unroll
    for (int cc = 0; cc < 2; cc++) {
      int c = w + cc * 4;                // chunk 0..7, wave-uniform
      const unsigned short* gk = Kb + (size_t)(kv0 + c * 8 + row) * 64 + (colb >> 1);
      __builtin_amdgcn_global_load_lds(
          (__attribute__((address_space(1))) void*)gk,
          (__attribute__((address_space(3))) void*)(lds + bufb * 4096 + c * 512), 16, 0, 0);
      const unsigned short* gv = Vb + (size_t)(c * 8 + row) * Tt + kv0 + (colb >> 1);
      __builtin_amdgcn_global_load_lds(
          (__attribute__((address_space(1))) void*)gv,
          (__attribute__((address_space(3))) void*)(lds + 8192 + bufb * 4096 + c * 512), 16, 0, 0);
    }
  };

  short8 q0 = *reinterpret_cast<const short8*>(Qb + (size_t)(qw0 + l15) * 64 + l4 * 8);
  short8 q1 = *reinterpret_cast<const short8*>(Qb + (size_t)(qw0 + l15) * 64 + 32 + l4 * 8);

  float m_run = -1e30f, l_run = 0.f;
  f32x4 oacc[4] = {};
  const int nt = qb + 1;

  stage(0, 0);
  __syncthreads();
  int cur = 0;
  for (int it = 0; it < nt - 1; ++it) {
    stage(cur ^ 1, (it + 1) * 64);       // async prefetch next tile
    attn_tile_lds<false>(lds + cur * 4096, lds + 8192 + cur * 4096,
                         w, l15, l4, q0, q1, m_run, l_run, oacc);
    __syncthreads();                      // drains vmcnt (stage) + lgkm (reads)
    cur ^= 1;
  }
  attn_tile_lds<true>(lds + cur * 4096, lds + 8192 + cur * 4096,
                      w, l15, l4, q0, q1, m_run, l_run, oacc);

  float inv = 1.0f / l_run;
  int t = qw0 + l15;
#pragma unroll
  for (int n = 0; n < 4; n++) {
    short4b o;
#pragma unroll
    for (int j = 0; j < 4; j++) o[j] = (short)f2b(oacc[n][j] * inv);
    *reinterpret_cast<short4b*>(
        &Y[((size_t)b * Tt + t) * Cc + h * 64 + n * 16 + l4 * 4]) = o;
  }
}

extern "C" void kernel_launch(void* const* d_in, const int* in_sizes, int n_in,
                              void* d_out, int out_size, void* d_ws, size_t ws_size,
                              hipStream_t stream) {
  (void)in_sizes; (void)n_in; (void)out_size; (void)ws_size;
  const float* x      = (const float*)d_in[0];
  const float* W_attn = (const float*)d_in[1];
  const float* b_attn = (const float*)d_in[2];
  const float* W_proj = (const float*)d_in[3];
  const float* b_proj = (const float*)d_in[4];
  const float* rope   = (const float*)d_in[5];
  float* out = (float*)d_out;

  char* ws = (char*)d_ws;
  unsigned short* xb  = (unsigned short*)(ws);                     // 8 MB
  unsigned short* WaT = (unsigned short*)(ws + (8u << 20));        // 6 MB
  unsigned short* WpT = (unsigned short*)(ws + (14u << 20));       // 2 MB
  unsigned short* qkv = (unsigned short*)(ws + (16u << 20));       // 24 MB
  unsigned short* Qs  = (unsigned short*)(ws + (40u << 20));       // 8 MB
  unsigned short* Ks  = (unsigned short*)(ws + (48u << 20));       // 8 MB
  unsigned short* Vt  = (unsigned short*)(ws + (56u << 20));       // 8 MB
  unsigned short* Yb  = (unsigned short*)(ws + (64u << 20));       // 8 MB  (total 72 MB)

  k_cast<<<2048, 256, 0, stream>>>(x, xb, BT * Cc);
  k_tcast<<<dim3(N1 / 32, Cc / 32), 256, 0, stream>>>(W_attn, WaT, Cc, N1);
  k_tcast<<<dim3(Cc / 32, Cc / 32), 256, 0, stream>>>(W_proj, WpT, Cc, Cc);
  k_gemm<1><<<dim3(N1 / 128, BT / 128), 256, 0, stream>>>(xb, WaT, b_attn, qkv, BT, N1, Cc);
  k_rope<<<Bb * Hh * (Tt / 64), 256, 0, stream>>>(qkv, rope, Qs, Ks, Vt);
  k_attn<<<Bb * Hh * (Tt / 64), 256, 0, stream>>>(Qs, Ks, Vt, Yb);
  k_gemm<0><<<dim3(Cc / 128, BT / 128), 256, 0, stream>>>(Yb, WpT, b_proj, out, BT, Cc, Cc);
}

// Round 4
// 168.599 us; speedup vs baseline: 2.5834x; 1.0161x over previous
//
#include <hip/hip_runtime.h>
#include <hip/hip_bf16.h>

typedef __attribute__((ext_vector_type(8))) short short8;
typedef __attribute__((ext_vector_type(4))) short short4b;
typedef __attribute__((ext_vector_type(4))) float f32x4;
typedef __attribute__((ext_vector_type(16))) float f32x16;
typedef __attribute__((ext_vector_type(4))) unsigned u32x4;

static constexpr int Bb = 2, Tt = 2048, Cc = 1024, Hh = 16;
static constexpr int BT = Bb * Tt;     // 4096
static constexpr int N1 = 3 * Cc;      // 3072

__device__ __forceinline__ unsigned short f2b(float f) {
  union { float f; unsigned u; } v; v.f = f;
  unsigned r = v.u + 0x7fffu + ((v.u >> 16) & 1u);
  return (unsigned short)(r >> 16);
}
__device__ __forceinline__ float b2f(short s) {
  union { unsigned u; float f; } v; v.u = ((unsigned)(unsigned short)s) << 16;
  return v.f;
}

// ---------------- cast f32 -> bf16, 8 elems/thread ----------------
__global__ __launch_bounds__(256) void k_cast(const float* __restrict__ in,
                                              unsigned short* __restrict__ out, int n) {
  int i = (blockIdx.x * 256 + threadIdx.x) * 8;
  if (i >= n) return;
  float4 a = *reinterpret_cast<const float4*>(in + i);
  float4 b = *reinterpret_cast<const float4*>(in + i + 4);
  short8 o;
  o[0] = f2b(a.x); o[1] = f2b(a.y); o[2] = f2b(a.z); o[3] = f2b(a.w);
  o[4] = f2b(b.x); o[5] = f2b(b.y); o[6] = f2b(b.z); o[7] = f2b(b.w);
  *reinterpret_cast<short8*>(out + i) = o;
}

// ------------- transpose + cast: in R x Ccol f32 -> out Ccol x R bf16 -------------
__global__ __launch_bounds__(256) void k_tcast(const float* __restrict__ in,
                                               unsigned short* __restrict__ out,
                                               int R, int Ccol) {
  __shared__ float tile[32][33];
  int cb = blockIdx.x * 32, rb = blockIdx.y * 32;
  int tx = threadIdx.x & 31, ty = threadIdx.x >> 5;  // ty 0..7
  for (int i = 0; i < 32; i += 8)
    tile[ty + i][tx] = in[(size_t)(rb + ty + i) * Ccol + cb + tx];
  __syncthreads();
  for (int i = 0; i < 32; i += 8)
    out[(size_t)(cb + ty + i) * R + rb + tx] = f2b(tile[tx][ty + i]);
}

// ---------------- bf16 GEMM: C(MxN) = A(MxK) * Bt(NxK)^T + bias ----------------
// 128x128 tile, BK=64, m97 structure + bijective XCD swizzle.
template <int OUT_BF16>
__global__ __launch_bounds__(256)
void k_gemm(const unsigned short* __restrict__ A, const unsigned short* __restrict__ Bt,
            const float* __restrict__ bias, void* __restrict__ Cout,
            int M, int N, int K) {
  __shared__ unsigned short Al[128 * 64];
  __shared__ unsigned short Bl[128 * 64];
  const int tid = threadIdx.x;
  const int lane = tid & 63;
  const int w = tid >> 6;
  const int wm = w >> 1, wn = w & 1;
  // XCD swizzle (grid.x*grid.y % 8 == 0 for both call sites)
  int nbx = gridDim.x;
  int lin = blockIdx.y * nbx + blockIdx.x;
  int cpx = (nbx * gridDim.y) >> 3;
  lin = (lin & 7) * cpx + (lin >> 3);
  const int mb = lin / nbx, nb = lin % nbx;
  const int l15 = lane & 15, l4 = lane >> 4;
  f32x4 acc[4][4] = {};

  const size_t arow0 = (size_t)mb * 128;
  const size_t brow0 = (size_t)nb * 128;

  for (int k0 = 0; k0 < K; k0 += 64) {
    __syncthreads();
#pragma unroll
    for (int cc = 0; cc < 4; cc++) {
      int c = w + cc * 4;                 // wave-uniform chunk id 0..15
      int e = c * 512 + lane * 8;         // bf16 element offset in 128x64 tile
      int row = e >> 6, col = e & 63;
      const unsigned short* ga = A + (arow0 + row) * (size_t)K + k0 + col;
      const unsigned short* gb = Bt + (brow0 + row) * (size_t)K + k0 + col;
      __builtin_amdgcn_global_load_lds((__attribute__((address_space(1))) void*)ga,
                                       (__attribute__((address_space(3))) void*)(Al + c * 512),
                                       16, 0, 0);
      __builtin_amdgcn_global_load_lds((__attribute__((address_space(1))) void*)gb,
                                       (__attribute__((address_space(3))) void*)(Bl + c * 512),
                                       16, 0, 0);
    }
    __syncthreads();
#pragma unroll
    for (int kc = 0; kc < 2; kc++) {
      short8 af[4], bfr[4];
#pragma unroll
      for (int m = 0; m < 4; m++)
        af[m] = *reinterpret_cast<const short8*>(&Al[(wm * 64 + m * 16 + l15) * 64 + kc * 32 + l4 * 8]);
#pragma unroll
      for (int n = 0; n < 4; n++)
        bfr[n] = *reinterpret_cast<const short8*>(&Bl[(wn * 64 + n * 16 + l15) * 64 + kc * 32 + l4 * 8]);
#pragma unroll
      for (int m = 0; m < 4; m++)
#pragma unroll
        for (int n = 0; n < 4; n++)
          acc[m][n] = __builtin_amdgcn_mfma_f32_16x16x32_bf16(af[m], bfr[n], acc[m][n], 0, 0, 0);
    }
  }

#pragma unroll
  for (int m = 0; m < 4; m++) {
#pragma unroll
    for (int n = 0; n < 4; n++) {
      int ccol = nb * 128 + wn * 64 + n * 16 + l15;
      float bv = bias ? bias[ccol] : 0.f;
#pragma unroll
      for (int j = 0; j < 4; j++) {
        int r = mb * 128 + wm * 64 + m * 16 + l4 * 4 + j;
        float v = acc[m][n][j] + bv;
        if (OUT_BF16)
          ((unsigned short*)Cout)[(size_t)r * N + ccol] = f2b(v);
        else
          ((float*)Cout)[(size_t)r * N + ccol] = v;
      }
    }
  }
}

// ---------------- RoPE + head relayout + V transpose ----------------
__global__ __launch_bounds__(256)
void k_rope(const unsigned short* __restrict__ qkv, const float* __restrict__ rope,
            unsigned short* __restrict__ Qs, unsigned short* __restrict__ Ks,
            unsigned short* __restrict__ Vt) {
  __shared__ unsigned short vt_l[64][72];  // 16B-aligned rows (144B stride)
  int bid = blockIdx.x;
  int tb = bid & 31, h = (bid >> 5) & 15, b = bid >> 9;
  int tid = threadIdx.x;
#pragma unroll
  for (int r = 0; r < 2; r++) {
    int e = (r * 256 + tid) * 8;
    int tl = e >> 6, d = e & 63;
    int t = tb * 64 + tl;
    const unsigned short* rowp = qkv + (size_t)(b * Tt + t) * 3072 + h * 64 + d;
    short8 qv = *reinterpret_cast<const short8*>(rowp);
    short8 kv = *reinterpret_cast<const short8*>(rowp + 1024);
    short8 vv = *reinterpret_cast<const short8*>(rowp + 2048);
    short8 qo, ko;
#pragma unroll
    for (int p = 0; p < 4; p++) {
      int j = (d >> 1) + p;
      float4 rv = *reinterpret_cast<const float4*>(rope + ((size_t)t * 32 + j) * 4);
      // rv = (cos, -sin, sin, cos)
      float xq = b2f(qv[2 * p]), yq = b2f(qv[2 * p + 1]);
      float xk = b2f(kv[2 * p]), yk = b2f(kv[2 * p + 1]);
      qo[2 * p]     = (short)f2b((xq * rv.x + yq * rv.y) * 0.125f);
      qo[2 * p + 1] = (short)f2b((xq * rv.z + yq * rv.w) * 0.125f);
      ko[2 * p]     = (short)f2b(xk * rv.x + yk * rv.y);
      ko[2 * p + 1] = (short)f2b(xk * rv.z + yk * rv.w);
    }
    size_t qdst = ((size_t)(b * 16 + h) * Tt + t) * 64 + d;
    *reinterpret_cast<short8*>(Qs + qdst) = qo;
    *reinterpret_cast<short8*>(Ks + qdst) = ko;
#pragma unroll
    for (int i2 = 0; i2 < 8; i2++) vt_l[d + i2][tl] = (unsigned short)vv[i2];
  }
  __syncthreads();
#pragma unroll
  for (int r = 0; r < 2; r++) {
    int e = (r * 256 + tid) * 8;
    int dl = e >> 6, tl = e & 63;
    short8 o = *reinterpret_cast<const short8*>(&vt_l[dl][tl]);
    *reinterpret_cast<short8*>(Vt + ((size_t)(b * 16 + h) * 64 + dl) * Tt + tb * 64 + tl) = o;
  }
}

// ---------------- causal flash attention: 32x32 swapped-QK^T, reg-resident P ------
// Per wave: 32 q-rows (q = lane&31), KVBLK=128 (4 key-tiles of 32).
// S^T via mfma_32x32x16(K_frag, Q_frag): lane holds 16 keys (C/D rows) per key-tile
// for its q-column. Softmax lane-local + one shfl_xor(32).
// P packed to bf16 pairs; partner half exchanged with 4 shfl_xor(32) per key-tile;
// PV: O^T += V^T * P^T via 32x32x16 at full K=16.
template <bool DIAG>
__device__ __forceinline__ void attn_tile128(
    const unsigned short* Kl, const unsigned short* Vl,
    int w, int l31, int hi, const short8 qf[4],
    float& m_run, float& l_run, f32x16 oacc[2]) {
  const int ktmax = DIAG ? w : 3;
  f32x16 s[4];
#pragma unroll
  for (int kt = 0; kt < 4; kt++) {
    if (kt > ktmax) continue;          // wave-uniform
    f32x16 acc = {};
    int rk = kt * 32 + l31;
    int sw = (rk & 7) << 4;
    const unsigned short* krow = Kl + rk * 64;
#pragma unroll
    for (int kk = 0; kk < 4; kk++) {
      short8 kf = *reinterpret_cast<const short8*>(krow + (((kk * 32 + hi * 16) ^ sw) >> 1));
      acc = __builtin_amdgcn_mfma_f32_32x32x16_bf16(kf, qf[kk], acc, 0, 0, 0);
    }
    if (DIAG && kt == w) {
#pragma unroll
      for (int r = 0; r < 16; r++) {
        int e = (r & 3) + 8 * (r >> 2) + 4 * hi;   // key offset within 32-tile
        if (e > l31) acc[r] = -1e30f;              // q offset = l31
      }
    }
    s[kt] = acc;
  }
  float mx = -1e30f;
#pragma unroll
  for (int kt = 0; kt < 4; kt++) {
    if (kt > ktmax) continue;
#pragma unroll
    for (int r = 0; r < 16; r++) mx = fmaxf(mx, s[kt][r]);
  }
  mx = fmaxf(mx, __shfl_xor(mx, 32));
  float nm = fmaxf(m_run, mx);
  float fsc = __expf(m_run - nm);
  m_run = nm;
#pragma unroll
  for (int dt = 0; dt < 2; dt++)
#pragma unroll
    for (int r = 0; r < 16; r++) oacc[dt][r] *= fsc;

  float psum = 0.f;
#pragma unroll
  for (int kt = 0; kt < 4; kt++) {
    if (kt > ktmax) continue;
    float p[16];
#pragma unroll
    for (int r = 0; r < 16; r++) { p[r] = __expf(s[kt][r] - nm); psum += p[r]; }
    unsigned P[8];
#pragma unroll
    for (int i = 0; i < 8; i++) {
      unsigned lo = (__builtin_bit_cast(unsigned, p[2 * i]) + 0x8000u) >> 16;
      unsigned h2 = (__builtin_bit_cast(unsigned, p[2 * i + 1]) + 0x8000u) & 0xffff0000u;
      P[i] = lo | h2;
    }
    // partner-half exchange (lane ^ 32)
    unsigned Y0 = (unsigned)__shfl_xor((int)(hi ? P[0] : P[2]), 32);
    unsigned Y1 = (unsigned)__shfl_xor((int)(hi ? P[1] : P[3]), 32);
    unsigned Y2 = (unsigned)__shfl_xor((int)(hi ? P[4] : P[6]), 32);
    unsigned Y3 = (unsigned)__shfl_xor((int)(hi ? P[5] : P[7]), 32);
    u32x4 c0 = hi ? u32x4{Y0, Y1, P[2], P[3]} : u32x4{P[0], P[1], Y0, Y1};
    u32x4 c1 = hi ? u32x4{Y2, Y3, P[6], P[7]} : u32x4{P[4], P[5], Y2, Y3};
    short8 pf0 = __builtin_bit_cast(short8, c0);
    short8 pf1 = __builtin_bit_cast(short8, c1);
#pragma unroll
    for (int dt = 0; dt < 2; dt++) {
      int d = dt * 32 + l31;
      int sv = (d & 15) << 4;
      const unsigned short* vrow = Vl + d * 128;   // 256B V rows
      short8 vf0 = *reinterpret_cast<const short8*>(vrow + (((kt * 64 + hi * 16) ^ sv) >> 1));
      short8 vf1 = *reinterpret_cast<const short8*>(vrow + (((kt * 64 + 32 + hi * 16) ^ sv) >> 1));
      oacc[dt] = __builtin_amdgcn_mfma_f32_32x32x16_bf16(vf0, pf0, oacc[dt], 0, 0, 0);
      oacc[dt] = __builtin_amdgcn_mfma_f32_32x32x16_bf16(vf1, pf1, oacc[dt], 0, 0, 0);
    }
  }
  psum += __shfl_xor(psum, 32);
  l_run = l_run * fsc + psum;
}

__global__ __launch_bounds__(256)
void k_attn(const unsigned short* __restrict__ Qs, const unsigned short* __restrict__ Ks,
            const unsigned short* __restrict__ Vt, unsigned short* __restrict__ Y) {
  __shared__ unsigned short lds[32768];  // 64KB: K0|K1 (16K shorts) + V0|V1 (16K)
  int tid = threadIdx.x, lane = tid & 63, w = tid >> 6;
  int bid = blockIdx.x;
  bid = (bid & 7) * 64 + (bid >> 3);     // XCD swizzle: 512 blocks
  int bh = bid >> 4, qb = bid & 15;
  int b = bh >> 4, h = bh & 15;
  int l31 = lane & 31, hi = lane >> 5;
  int qB0 = qb * 128;
  int qw0 = qB0 + w * 32;
  const unsigned short* Qb = Qs + (size_t)bh * Tt * 64;
  const unsigned short* Kb = Ks + (size_t)bh * Tt * 64;
  const unsigned short* Vb = Vt + (size_t)bh * 64 * Tt;

  // stage 128-key tile: K 128rows x 64d (128B rows, 3-bit swizzle),
  //                     V^T 64 d-rows x 128 keys (256B rows, 4-bit swizzle).
  auto stage = [&](int buf, int kv0) {
    unsigned short* Kbuf = lds + buf * 8192;
    unsigned short* Vbuf = lds + 16384 + buf * 8192;
    int krow = lane >> 3;
    int kcolb = ((lane & 7) * 16) ^ ((krow & 7) << 4);
#pragma unroll
    for (int cc = 0; cc < 4; cc++) {
      int c = w + cc * 4;                // wave-uniform chunk 0..15
      const unsigned short* gk = Kb + (size_t)(kv0 + c * 8 + krow) * 64 + (kcolb >> 1);
      __builtin_amdgcn_global_load_lds((const __attribute__((address_space(1))) void*)gk,
          (__attribute__((address_space(3))) void*)(Kbuf + c * 512), 16, 0, 0);
      int vr = c * 4 + (lane >> 4);
      int vcolb = ((lane & 15) * 16) ^ ((vr & 15) << 4);
      const unsigned short* gv = Vb + (size_t)vr * Tt + kv0 + (vcolb >> 1);
      __builtin_amdgcn_global_load_lds((const __attribute__((address_space(1))) void*)gv,
          (__attribute__((address_space(3))) void*)(Vbuf + c * 512), 16, 0, 0);
    }
  };

  short8 qf[4];
#pragma unroll
  for (int kk = 0; kk < 4; kk++)
    qf[kk] = *reinterpret_cast<const short8*>(Qb + (size_t)(qw0 + l31) * 64 + kk * 16 + hi * 8);

  float m_run = -1e30f, l_run = 0.f;
  f32x16 oacc[2] = {};
  const int nt = qb + 1;

  stage(0, 0);
  __syncthreads();
  int cur = 0;
  for (int it = 0; it < nt - 1; ++it) {
    stage(cur ^ 1, (it + 1) * 128);      // async prefetch next tile
    attn_tile128<false>(lds + cur * 8192, lds + 16384 + cur * 8192,
                        w, l31, hi, qf, m_run, l_run, oacc);
    __syncthreads();                     // drains vmcnt (stage) + lgkm
    cur ^= 1;
  }
  attn_tile128<true>(lds + cur * 8192, lds + 16384 + cur * 8192,
                     w, l31, hi, qf, m_run, l_run, oacc);

  float inv = 1.0f / l_run;
  int t = qw0 + l31;
  unsigned short* yrow = Y + ((size_t)b * Tt + t) * Cc + h * 64;
#pragma unroll
  for (int dt = 0; dt < 2; dt++)
#pragma unroll
    for (int q4 = 0; q4 < 4; q4++) {
      short4b o;
#pragma unroll
      for (int j = 0; j < 4; j++) o[j] = (short)f2b(oacc[dt][q4 * 4 + j] * inv);
      *reinterpret_cast<short4b*>(yrow + dt * 32 + q4 * 8 + hi * 4) = o;
    }
}

extern "C" void kernel_launch(void* const* d_in, const int* in_sizes, int n_in,
                              void* d_out, int out_size, void* d_ws, size_t ws_size,
                              hipStream_t stream) {
  (void)in_sizes; (void)n_in; (void)out_size; (void)ws_size;
  const float* x      = (const float*)d_in[0];
  const float* W_attn = (const float*)d_in[1];
  const float* b_attn = (const float*)d_in[2];
  const float* W_proj = (const float*)d_in[3];
  const float* b_proj = (const float*)d_in[4];
  const float* rope   = (const float*)d_in[5];
  float* out = (float*)d_out;

  char* ws = (char*)d_ws;
  unsigned short* xb  = (unsigned short*)(ws);                     // 8 MB
  unsigned short* WaT = (unsigned short*)(ws + (8u << 20));        // 6 MB
  unsigned short* WpT = (unsigned short*)(ws + (14u << 20));       // 2 MB
  unsigned short* qkv = (unsigned short*)(ws + (16u << 20));       // 24 MB
  unsigned short* Qs  = (unsigned short*)(ws + (40u << 20));       // 8 MB
  unsigned short* Ks  = (unsigned short*)(ws + (48u << 20));       // 8 MB
  unsigned short* Vt  = (unsigned short*)(ws + (56u << 20));       // 8 MB
  unsigned short* Yb  = (unsigned short*)(ws + (64u << 20));       // 8 MB  (total 72 MB)

  k_cast<<<2048, 256, 0, stream>>>(x, xb, BT * Cc);
  k_tcast<<<dim3(N1 / 32, Cc / 32), 256, 0, stream>>>(W_attn, WaT, Cc, N1);
  k_tcast<<<dim3(Cc / 32, Cc / 32), 256, 0, stream>>>(W_proj, WpT, Cc, Cc);
  k_gemm<1><<<dim3(N1 / 128, BT / 128), 256, 0, stream>>>(xb, WaT, b_attn, qkv, BT, N1, Cc);
  k_rope<<<Bb * Hh * (Tt / 64), 256, 0, stream>>>(qkv, rope, Qs, Ks, Vt);
  k_attn<<<Bb * Hh * (Tt / 128), 256, 0, stream>>>(Qs, Ks, Vt, Yb);
  k_gemm<0><<<dim3(Cc / 128, BT / 128), 256, 0, stream>>>(Yb, WpT, b_proj, out, BT, Cc, Cc);
}

// Round 5
// 154.187 us; speedup vs baseline: 2.8249x; 1.0935x over previous
//
#include <hip/hip_runtime.h>
#include <hip/hip_bf16.h>

typedef __attribute__((ext_vector_type(8))) short short8;
typedef __attribute__((ext_vector_type(4))) short short4b;
typedef __attribute__((ext_vector_type(4))) float f32x4;
typedef __attribute__((ext_vector_type(16))) float f32x16;
typedef __attribute__((ext_vector_type(4))) unsigned u32x4;

static constexpr int Bb = 2, Tt = 2048, Cc = 1024, Hh = 16;
static constexpr int BT = Bb * Tt;     // 4096
static constexpr int N1 = 3 * Cc;      // 3072

__device__ __forceinline__ unsigned short f2b(float f) {
  union { float f; unsigned u; } v; v.f = f;
  unsigned r = v.u + 0x7fffu + ((v.u >> 16) & 1u);
  return (unsigned short)(r >> 16);
}
__device__ __forceinline__ float b2f(short s) {
  union { unsigned u; float f; } v; v.u = ((unsigned)(unsigned short)s) << 16;
  return v.f;
}

// ---------------- cast f32 -> bf16, 8 elems/thread ----------------
__global__ __launch_bounds__(256) void k_cast(const float* __restrict__ in,
                                              unsigned short* __restrict__ out, int n) {
  int i = (blockIdx.x * 256 + threadIdx.x) * 8;
  if (i >= n) return;
  float4 a = *reinterpret_cast<const float4*>(in + i);
  float4 b = *reinterpret_cast<const float4*>(in + i + 4);
  short8 o;
  o[0] = f2b(a.x); o[1] = f2b(a.y); o[2] = f2b(a.z); o[3] = f2b(a.w);
  o[4] = f2b(b.x); o[5] = f2b(b.y); o[6] = f2b(b.z); o[7] = f2b(b.w);
  *reinterpret_cast<short8*>(out + i) = o;
}

// ------------- transpose + cast: in R x Ccol f32 -> out Ccol x R bf16 -------------
__global__ __launch_bounds__(256) void k_tcast(const float* __restrict__ in,
                                               unsigned short* __restrict__ out,
                                               int R, int Ccol) {
  __shared__ float tile[32][33];
  int cb = blockIdx.x * 32, rb = blockIdx.y * 32;
  int tx = threadIdx.x & 31, ty = threadIdx.x >> 5;  // ty 0..7
  for (int i = 0; i < 32; i += 8)
    tile[ty + i][tx] = in[(size_t)(rb + ty + i) * Ccol + cb + tx];
  __syncthreads();
  for (int i = 0; i < 32; i += 8)
    out[(size_t)(cb + ty + i) * R + rb + tx] = f2b(tile[tx][ty + i]);
}

// ---------------- bf16 GEMM: C(MxN) = A(MxK) * Bt(NxK)^T + bias ----------------
// 128x128 tile, BK=64, m97 structure + bijective XCD swizzle.
template <int OUT_BF16>
__global__ __launch_bounds__(256)
void k_gemm(const unsigned short* __restrict__ A, const unsigned short* __restrict__ Bt,
            const float* __restrict__ bias, void* __restrict__ Cout,
            int M, int N, int K) {
  __shared__ unsigned short Al[128 * 64];
  __shared__ unsigned short Bl[128 * 64];
  const int tid = threadIdx.x;
  const int lane = tid & 63;
  const int w = tid >> 6;
  const int wm = w >> 1, wn = w & 1;
  // XCD swizzle (grid.x*grid.y % 8 == 0 for both call sites)
  int nbx = gridDim.x;
  int lin = blockIdx.y * nbx + blockIdx.x;
  int cpx = (nbx * gridDim.y) >> 3;
  lin = (lin & 7) * cpx + (lin >> 3);
  const int mb = lin / nbx, nb = lin % nbx;
  const int l15 = lane & 15, l4 = lane >> 4;
  f32x4 acc[4][4] = {};

  const size_t arow0 = (size_t)mb * 128;
  const size_t brow0 = (size_t)nb * 128;

  for (int k0 = 0; k0 < K; k0 += 64) {
    __syncthreads();
#pragma unroll
    for (int cc = 0; cc < 4; cc++) {
      int c = w + cc * 4;                 // wave-uniform chunk id 0..15
      int e = c * 512 + lane * 8;         // bf16 element offset in 128x64 tile
      int row = e >> 6, col = e & 63;
      const unsigned short* ga = A + (arow0 + row) * (size_t)K + k0 + col;
      const unsigned short* gb = Bt + (brow0 + row) * (size_t)K + k0 + col;
      __builtin_amdgcn_global_load_lds((__attribute__((address_space(1))) void*)ga,
                                       (__attribute__((address_space(3))) void*)(Al + c * 512),
                                       16, 0, 0);
      __builtin_amdgcn_global_load_lds((__attribute__((address_space(1))) void*)gb,
                                       (__attribute__((address_space(3))) void*)(Bl + c * 512),
                                       16, 0, 0);
    }
    __syncthreads();
#pragma unroll
    for (int kc = 0; kc < 2; kc++) {
      short8 af[4], bfr[4];
#pragma unroll
      for (int m = 0; m < 4; m++)
        af[m] = *reinterpret_cast<const short8*>(&Al[(wm * 64 + m * 16 + l15) * 64 + kc * 32 + l4 * 8]);
#pragma unroll
      for (int n = 0; n < 4; n++)
        bfr[n] = *reinterpret_cast<const short8*>(&Bl[(wn * 64 + n * 16 + l15) * 64 + kc * 32 + l4 * 8]);
#pragma unroll
      for (int m = 0; m < 4; m++)
#pragma unroll
        for (int n = 0; n < 4; n++)
          acc[m][n] = __builtin_amdgcn_mfma_f32_16x16x32_bf16(af[m], bfr[n], acc[m][n], 0, 0, 0);
    }
  }

#pragma unroll
  for (int m = 0; m < 4; m++) {
#pragma unroll
    for (int n = 0; n < 4; n++) {
      int ccol = nb * 128 + wn * 64 + n * 16 + l15;
      float bv = bias ? bias[ccol] : 0.f;
#pragma unroll
      for (int j = 0; j < 4; j++) {
        int r = mb * 128 + wm * 64 + m * 16 + l4 * 4 + j;
        float v = acc[m][n][j] + bv;
        if (OUT_BF16)
          ((unsigned short*)Cout)[(size_t)r * N + ccol] = f2b(v);
        else
          ((float*)Cout)[(size_t)r * N + ccol] = v;
      }
    }
  }
}

// ---------------- RoPE + head relayout + V transpose ----------------
// Q pre-scaled by (1/sqrt(64)) * log2(e) so attention can use exp2 directly.
__global__ __launch_bounds__(256)
void k_rope(const unsigned short* __restrict__ qkv, const float* __restrict__ rope,
            unsigned short* __restrict__ Qs, unsigned short* __restrict__ Ks,
            unsigned short* __restrict__ Vt) {
  __shared__ unsigned short vt_l[64][72];  // 16B-aligned rows (144B stride)
  const float QS = 0.125f * 1.44269504f;
  int bid = blockIdx.x;
  int tb = bid & 31, h = (bid >> 5) & 15, b = bid >> 9;
  int tid = threadIdx.x;
#pragma unroll
  for (int r = 0; r < 2; r++) {
    int e = (r * 256 + tid) * 8;
    int tl = e >> 6, d = e & 63;
    int t = tb * 64 + tl;
    const unsigned short* rowp = qkv + (size_t)(b * Tt + t) * 3072 + h * 64 + d;
    short8 qv = *reinterpret_cast<const short8*>(rowp);
    short8 kv = *reinterpret_cast<const short8*>(rowp + 1024);
    short8 vv = *reinterpret_cast<const short8*>(rowp + 2048);
    short8 qo, ko;
#pragma unroll
    for (int p = 0; p < 4; p++) {
      int j = (d >> 1) + p;
      float4 rv = *reinterpret_cast<const float4*>(rope + ((size_t)t * 32 + j) * 4);
      // rv = (cos, -sin, sin, cos)
      float xq = b2f(qv[2 * p]), yq = b2f(qv[2 * p + 1]);
      float xk = b2f(kv[2 * p]), yk = b2f(kv[2 * p + 1]);
      qo[2 * p]     = (short)f2b((xq * rv.x + yq * rv.y) * QS);
      qo[2 * p + 1] = (short)f2b((xq * rv.z + yq * rv.w) * QS);
      ko[2 * p]     = (short)f2b(xk * rv.x + yk * rv.y);
      ko[2 * p + 1] = (short)f2b(xk * rv.z + yk * rv.w);
    }
    size_t qdst = ((size_t)(b * 16 + h) * Tt + t) * 64 + d;
    *reinterpret_cast<short8*>(Qs + qdst) = qo;
    *reinterpret_cast<short8*>(Ks + qdst) = ko;
#pragma unroll
    for (int i2 = 0; i2 < 8; i2++) vt_l[d + i2][tl] = (unsigned short)vv[i2];
  }
  __syncthreads();
#pragma unroll
  for (int r = 0; r < 2; r++) {
    int e = (r * 256 + tid) * 8;
    int dl = e >> 6, tl = e & 63;
    short8 o = *reinterpret_cast<const short8*>(&vt_l[dl][tl]);
    *reinterpret_cast<short8*>(Vt + ((size_t)(b * 16 + h) * 64 + dl) * Tt + tb * 64 + tl) = o;
  }
}

__device__ __forceinline__ float tmax16(const f32x16& v) {
  float a0 = fmaxf(v[0], v[1]),   a1 = fmaxf(v[2], v[3]);
  float a2 = fmaxf(v[4], v[5]),   a3 = fmaxf(v[6], v[7]);
  float a4 = fmaxf(v[8], v[9]),   a5 = fmaxf(v[10], v[11]);
  float a6 = fmaxf(v[12], v[13]), a7 = fmaxf(v[14], v[15]);
  float b0 = fmaxf(a0, a1), b1 = fmaxf(a2, a3), b2 = fmaxf(a4, a5), b3 = fmaxf(a6, a7);
  return fmaxf(fmaxf(b0, b1), fmaxf(b2, b3));
}

// ---------------- causal flash attention: 32x32 swapped-QK^T, reg-resident P ------
// Per wave: 32 q-rows (q = lane&31), KVBLK=128 (4 key-tiles of 32).
// exp2-domain softmax (Q pre-scaled by log2e/8); tree reductions.
template <bool DIAG>
__device__ __forceinline__ void attn_tile128(
    const unsigned short* Kl, const unsigned short* Vl,
    int w, int l31, int hi, const short8 qf[4],
    float& m_run, float& l_run, f32x16 oacc[2]) {
  const int ktmax = DIAG ? w : 3;
  f32x16 s[4];
#pragma unroll
  for (int kt = 0; kt < 4; kt++) {
    if (kt > ktmax) continue;          // wave-uniform
    f32x16 acc = {};
    int rk = kt * 32 + l31;
    int sw = (rk & 7) << 4;
    const unsigned short* krow = Kl + rk * 64;
#pragma unroll
    for (int kk = 0; kk < 4; kk++) {
      short8 kf = *reinterpret_cast<const short8*>(krow + (((kk * 32 + hi * 16) ^ sw) >> 1));
      acc = __builtin_amdgcn_mfma_f32_32x32x16_bf16(kf, qf[kk], acc, 0, 0, 0);
    }
    if (DIAG && kt == w) {
#pragma unroll
      for (int r = 0; r < 16; r++) {
        int e = (r & 3) + 8 * (r >> 2) + 4 * hi;   // key offset within 32-tile
        if (e > l31) acc[r] = -1e30f;              // q offset = l31
      }
    }
    s[kt] = acc;
  }
  float km[4];
#pragma unroll
  for (int kt = 0; kt < 4; kt++) km[kt] = (kt <= ktmax) ? tmax16(s[kt]) : -1e30f;
  float mx = fmaxf(fmaxf(km[0], km[1]), fmaxf(km[2], km[3]));
  mx = fmaxf(mx, __shfl_xor(mx, 32));
  float nm = fmaxf(m_run, mx);
  float fsc = __builtin_amdgcn_exp2f(m_run - nm);
  m_run = nm;
#pragma unroll
  for (int dt = 0; dt < 2; dt++)
#pragma unroll
    for (int r = 0; r < 16; r++) oacc[dt][r] *= fsc;

  float kps[4] = {0.f, 0.f, 0.f, 0.f};
#pragma unroll
  for (int kt = 0; kt < 4; kt++) {
    if (kt > ktmax) continue;
    float p[16];
#pragma unroll
    for (int r = 0; r < 16; r++) p[r] = __builtin_amdgcn_exp2f(s[kt][r] - nm);
    float s0 = (p[0] + p[1]) + (p[2] + p[3]);
    float s1 = (p[4] + p[5]) + (p[6] + p[7]);
    float s2 = (p[8] + p[9]) + (p[10] + p[11]);
    float s3 = (p[12] + p[13]) + (p[14] + p[15]);
    kps[kt] = (s0 + s1) + (s2 + s3);
    unsigned P[8];
#pragma unroll
    for (int i = 0; i < 8; i++) {
      unsigned lo = (__builtin_bit_cast(unsigned, p[2 * i]) + 0x8000u) >> 16;
      unsigned h2 = (__builtin_bit_cast(unsigned, p[2 * i + 1]) + 0x8000u) & 0xffff0000u;
      P[i] = lo | h2;
    }
    // partner-half exchange (lane ^ 32)
    unsigned Y0 = (unsigned)__shfl_xor((int)(hi ? P[0] : P[2]), 32);
    unsigned Y1 = (unsigned)__shfl_xor((int)(hi ? P[1] : P[3]), 32);
    unsigned Y2 = (unsigned)__shfl_xor((int)(hi ? P[4] : P[6]), 32);
    unsigned Y3 = (unsigned)__shfl_xor((int)(hi ? P[5] : P[7]), 32);
    u32x4 c0 = hi ? u32x4{Y0, Y1, P[2], P[3]} : u32x4{P[0], P[1], Y0, Y1};
    u32x4 c1 = hi ? u32x4{Y2, Y3, P[6], P[7]} : u32x4{P[4], P[5], Y2, Y3};
    short8 pf0 = __builtin_bit_cast(short8, c0);
    short8 pf1 = __builtin_bit_cast(short8, c1);
#pragma unroll
    for (int dt = 0; dt < 2; dt++) {
      int d = dt * 32 + l31;
      int sv = (d & 15) << 4;
      const unsigned short* vrow = Vl + d * 128;   // 256B V rows
      short8 vf0 = *reinterpret_cast<const short8*>(vrow + (((kt * 64 + hi * 16) ^ sv) >> 1));
      short8 vf1 = *reinterpret_cast<const short8*>(vrow + (((kt * 64 + 32 + hi * 16) ^ sv) >> 1));
      oacc[dt] = __builtin_amdgcn_mfma_f32_32x32x16_bf16(vf0, pf0, oacc[dt], 0, 0, 0);
      oacc[dt] = __builtin_amdgcn_mfma_f32_32x32x16_bf16(vf1, pf1, oacc[dt], 0, 0, 0);
    }
  }
  float psum = (kps[0] + kps[1]) + (kps[2] + kps[3]);
  psum += __shfl_xor(psum, 32);
  l_run = l_run * fsc + psum;
}

__global__ __launch_bounds__(256)
void k_attn(const unsigned short* __restrict__ Qs, const unsigned short* __restrict__ Ks,
            const unsigned short* __restrict__ Vt, unsigned short* __restrict__ Y) {
  __shared__ unsigned short lds[32768];  // 64KB: K0|K1 (16K shorts) + V0|V1 (16K)
  int tid = threadIdx.x, lane = tid & 63, w = tid >> 6;
  // Complementary-pair dispatch: blocks s and s+256 share (bh,j) and get
  // qb = 15-j and qb = j -> per-CU work sums to 17 units under round-robin
  // block->CU assignment. Heavy half (qb=15-j) dispatched first.
  int s = blockIdx.x;                  // 0..511
  int half = s >> 8;
  int p = s & 255;
  int bh = p >> 3;                     // 0..31
  int j = p & 7;
  int qb = half ? j : 15 - j;
  int b = bh >> 4, h = bh & 15;
  int l31 = lane & 31, hi = lane >> 5;
  int qw0 = qb * 128 + w * 32;
  const unsigned short* Qb = Qs + (size_t)bh * Tt * 64;
  const unsigned short* Kb = Ks + (size_t)bh * Tt * 64;
  const unsigned short* Vb = Vt + (size_t)bh * 64 * Tt;

  // stage 128-key tile: K 128rows x 64d (128B rows, 3-bit swizzle),
  //                     V^T 64 d-rows x 128 keys (256B rows, 4-bit swizzle).
  auto stage = [&](int buf, int kv0) {
    unsigned short* Kbuf = lds + buf * 8192;
    unsigned short* Vbuf = lds + 16384 + buf * 8192;
    int krow = lane >> 3;
    int kcolb = ((lane & 7) * 16) ^ ((krow & 7) << 4);
#pragma unroll
    for (int cc = 0; cc < 4; cc++) {
      int c = w + cc * 4;                // wave-uniform chunk 0..15
      const unsigned short* gk = Kb + (size_t)(kv0 + c * 8 + krow) * 64 + (kcolb >> 1);
      __builtin_amdgcn_global_load_lds((const __attribute__((address_space(1))) void*)gk,
          (__attribute__((address_space(3))) void*)(Kbuf + c * 512), 16, 0, 0);
      int vr = c * 4 + (lane >> 4);
      int vcolb = ((lane & 15) * 16) ^ ((vr & 15) << 4);
      const unsigned short* gv = Vb + (size_t)vr * Tt + kv0 + (vcolb >> 1);
      __builtin_amdgcn_global_load_lds((const __attribute__((address_space(1))) void*)gv,
          (__attribute__((address_space(3))) void*)(Vbuf + c * 512), 16, 0, 0);
    }
  };

  short8 qf[4];
#pragma unroll
  for (int kk = 0; kk < 4; kk++)
    qf[kk] = *reinterpret_cast<const short8*>(Qb + (size_t)(qw0 + l31) * 64 + kk * 16 + hi * 8);

  float m_run = -1e30f, l_run = 0.f;
  f32x16 oacc[2] = {};
  const int nt = qb + 1;

  stage(0, 0);
  __syncthreads();
  int cur = 0;
  for (int it = 0; it < nt - 1; ++it) {
    stage(cur ^ 1, (it + 1) * 128);      // async prefetch next tile
    attn_tile128<false>(lds + cur * 8192, lds + 16384 + cur * 8192,
                        w, l31, hi, qf, m_run, l_run, oacc);
    __syncthreads();                     // drains vmcnt (stage) + lgkm
    cur ^= 1;
  }
  attn_tile128<true>(lds + cur * 8192, lds + 16384 + cur * 8192,
                     w, l31, hi, qf, m_run, l_run, oacc);

  float inv = 1.0f / l_run;
  int t = qw0 + l31;
  unsigned short* yrow = Y + ((size_t)b * Tt + t) * Cc + h * 64;
#pragma unroll
  for (int dt = 0; dt < 2; dt++)
#pragma unroll
    for (int q4 = 0; q4 < 4; q4++) {
      short4b o;
#pragma unroll
      for (int jj = 0; jj < 4; jj++) o[jj] = (short)f2b(oacc[dt][q4 * 4 + jj] * inv);
      *reinterpret_cast<short4b*>(yrow + dt * 32 + q4 * 8 + hi * 4) = o;
    }
}

extern "C" void kernel_launch(void* const* d_in, const int* in_sizes, int n_in,
                              void* d_out, int out_size, void* d_ws, size_t ws_size,
                              hipStream_t stream) {
  (void)in_sizes; (void)n_in; (void)out_size; (void)ws_size;
  const float* x      = (const float*)d_in[0];
  const float* W_attn = (const float*)d_in[1];
  const float* b_attn = (const float*)d_in[2];
  const float* W_proj = (const float*)d_in[3];
  const float* b_proj = (const float*)d_in[4];
  const float* rope   = (const float*)d_in[5];
  float* out = (float*)d_out;

  char* ws = (char*)d_ws;
  unsigned short* xb  = (unsigned short*)(ws);                     // 8 MB
  unsigned short* WaT = (unsigned short*)(ws + (8u << 20));        // 6 MB
  unsigned short* WpT = (unsigned short*)(ws + (14u << 20));       // 2 MB
  unsigned short* qkv = (unsigned short*)(ws + (16u << 20));       // 24 MB
  unsigned short* Qs  = (unsigned short*)(ws + (40u << 20));       // 8 MB
  unsigned short* Ks  = (unsigned short*)(ws + (48u << 20));       // 8 MB
  unsigned short* Vt  = (unsigned short*)(ws + (56u << 20));       // 8 MB
  unsigned short* Yb  = (unsigned short*)(ws + (64u << 20));       // 8 MB  (total 72 MB)

  k_cast<<<2048, 256, 0, stream>>>(x, xb, BT * Cc);
  k_tcast<<<dim3(N1 / 32, Cc / 32), 256, 0, stream>>>(W_attn, WaT, Cc, N1);
  k_tcast<<<dim3(Cc / 32, Cc / 32), 256, 0, stream>>>(W_proj, WpT, Cc, Cc);
  k_gemm<1><<<dim3(N1 / 128, BT / 128), 256, 0, stream>>>(xb, WaT, b_attn, qkv, BT, N1, Cc);
  k_rope<<<Bb * Hh * (Tt / 64), 256, 0, stream>>>(qkv, rope, Qs, Ks, Vt);
  k_attn<<<Bb * Hh * (Tt / 128), 256, 0, stream>>>(Qs, Ks, Vt, Yb);
  k_gemm<0><<<dim3(Cc / 128, BT / 128), 256, 0, stream>>>(Yb, WpT, b_proj, out, BT, Cc, Cc);
}

// Round 6
// 121.930 us; speedup vs baseline: 3.5722x; 1.2646x over previous
//
#include <hip/hip_runtime.h>
#include <hip/hip_bf16.h>

typedef __attribute__((ext_vector_type(8))) short short8;
typedef __attribute__((ext_vector_type(4))) short short4b;
typedef __attribute__((ext_vector_type(4))) float f32x4;
typedef __attribute__((ext_vector_type(16))) float f32x16;
typedef __attribute__((ext_vector_type(4))) unsigned u32x4;

static constexpr int Bb = 2, Tt = 2048, Cc = 1024, Hh = 16;
static constexpr int BT = Bb * Tt;     // 4096
static constexpr int N1 = 3 * Cc;      // 3072

__device__ __forceinline__ unsigned short f2b(float f) {
  union { float f; unsigned u; } v; v.f = f;
  unsigned r = v.u + 0x7fffu + ((v.u >> 16) & 1u);
  return (unsigned short)(r >> 16);
}
__device__ __forceinline__ float b2f(short s) {
  union { unsigned u; float f; } v; v.u = ((unsigned)(unsigned short)s) << 16;
  return v.f;
}

// ---------------- cast f32 -> bf16, 8 elems/thread ----------------
__global__ __launch_bounds__(256) void k_cast(const float* __restrict__ in,
                                              unsigned short* __restrict__ out, int n) {
  int i = (blockIdx.x * 256 + threadIdx.x) * 8;
  if (i >= n) return;
  float4 a = *reinterpret_cast<const float4*>(in + i);
  float4 b = *reinterpret_cast<const float4*>(in + i + 4);
  short8 o;
  o[0] = f2b(a.x); o[1] = f2b(a.y); o[2] = f2b(a.z); o[3] = f2b(a.w);
  o[4] = f2b(b.x); o[5] = f2b(b.y); o[6] = f2b(b.z); o[7] = f2b(b.w);
  *reinterpret_cast<short8*>(out + i) = o;
}

// ------------- transpose + cast: in R x Ccol f32 -> out Ccol x R bf16 -------------
__global__ __launch_bounds__(256) void k_tcast(const float* __restrict__ in,
                                               unsigned short* __restrict__ out,
                                               int R, int Ccol) {
  __shared__ float tile[32][33];
  int cb = blockIdx.x * 32, rb = blockIdx.y * 32;
  int tx = threadIdx.x & 31, ty = threadIdx.x >> 5;  // ty 0..7
  for (int i = 0; i < 32; i += 8)
    tile[ty + i][tx] = in[(size_t)(rb + ty + i) * Ccol + cb + tx];
  __syncthreads();
  for (int i = 0; i < 32; i += 8)
    out[(size_t)(cb + ty + i) * R + rb + tx] = f2b(tile[tx][ty + i]);
}

// ---------------- 8-wave phase-split GEMM: C(MxN) = A(MxK)*Bt(NxK)^T + bias -------
// BM=256, BN=NF*64, BK=64, 8 waves (2M x 4N), per-wave 128 x NF*16.
// Double-buffered LDS, T2 both-sides swizzle, NF phases/K-tile, setprio MFMA
// clusters, single boundary vmcnt(0) per K-tile (drains loads issued NF phases ago).
template <int NF, int OUT_BF16>
__global__ __launch_bounds__(512, 2)
void k_gemm8(const unsigned short* __restrict__ A, const unsigned short* __restrict__ Bt,
             const float* __restrict__ bias, void* __restrict__ Cout,
             int M, int N, int K) {
  constexpr int BN = NF * 64;
  constexpr int ASZ = 256 * 64;          // shorts
  constexpr int BSZ = BN * 64;
  constexpr int STRIDE = ASZ + BSZ;
  extern __shared__ unsigned short lds[];
  const int tid = threadIdx.x, lane = tid & 63, w = tid >> 6;
  const int wm = w >> 2, wn = w & 3;
  const int l15 = lane & 15, l4 = lane >> 4;
  int nbx = gridDim.x;
  int lin = blockIdx.y * nbx + blockIdx.x;
  int cpx = (nbx * gridDim.y) >> 3;      // grid % 8 == 0 at both call sites
  lin = (lin & 7) * cpx + (lin >> 3);
  const int mb = lin / nbx, nb = lin % nbx;
  const size_t arow0 = (size_t)mb * 256;
  const size_t brow0 = (size_t)nb * BN;

  // staging: linear LDS dest, pre-swizzled global source col (rule 21);
  // row&7 == lane>>3 for every chunk since chunks are 8 rows.
  const int srow = lane >> 3;
  const int scol = (((lane & 7) * 16) ^ (srow << 4)) >> 1;  // elems
  auto stage = [&](int buf, int k0) {
    unsigned short* Ab = lds + buf * STRIDE;
    unsigned short* Bb = Ab + ASZ;
#pragma unroll
    for (int i = 0; i < 4; i++) {
      int c = w + 8 * i;
      const unsigned short* g = A + (arow0 + c * 8 + srow) * (size_t)K + k0 + scol;
      __builtin_amdgcn_global_load_lds((const __attribute__((address_space(1))) void*)g,
          (__attribute__((address_space(3))) void*)(Ab + c * 512), 16, 0, 0);
    }
#pragma unroll
    for (int i = 0; i < NF; i++) {
      int c = w + 8 * i;
      const unsigned short* g = Bt + (brow0 + c * 8 + srow) * (size_t)K + k0 + scol;
      __builtin_amdgcn_global_load_lds((const __attribute__((address_space(1))) void*)g,
          (__attribute__((address_space(3))) void*)(Bb + c * 512), 16, 0, 0);
    }
  };

  f32x4 acc[8][NF] = {};
  const int NK = K >> 6;

  stage(0, 0);
  asm volatile("s_waitcnt vmcnt(0)" ::: "memory");
  asm volatile("s_barrier" ::: "memory");

  for (int kt = 0; kt < NK; kt++) {
    int buf = kt & 1;
    if (kt + 1 < NK) stage(buf ^ 1, (kt + 1) << 6);   // prefetch next K-tile
    const unsigned short* Ab = lds + buf * STRIDE;
    const unsigned short* Bb = Ab + ASZ;
    short8 af[8][2];
#pragma unroll
    for (int p = 0; p < NF; p++) {
      if (p == 0) {
#pragma unroll
        for (int m = 0; m < 8; m++) {
          int ra = wm * 128 + m * 16 + l15;
#pragma unroll
          for (int kk = 0; kk < 2; kk++) {
            int cb = (kk * 64 + l4 * 16) ^ ((ra & 7) << 4);
            af[m][kk] = *reinterpret_cast<const short8*>(Ab + ra * 64 + (cb >> 1));
          }
        }
      }
      short8 bfr[2];
      int rb = wn * (NF * 16) + p * 16 + l15;
#pragma unroll
      for (int kk = 0; kk < 2; kk++) {
        int cb = (kk * 64 + l4 * 16) ^ ((rb & 7) << 4);
        bfr[kk] = *reinterpret_cast<const short8*>(Bb + rb * 64 + (cb >> 1));
      }
      asm volatile("s_barrier" ::: "memory");
      asm volatile("s_waitcnt lgkmcnt(0)" ::: "memory");
      __builtin_amdgcn_sched_barrier(0);
      __builtin_amdgcn_s_setprio(1);
#pragma unroll
      for (int m = 0; m < 8; m++) {
        acc[m][p] = __builtin_amdgcn_mfma_f32_16x16x32_bf16(af[m][0], bfr[0], acc[m][p], 0, 0, 0);
        acc[m][p] = __builtin_amdgcn_mfma_f32_16x16x32_bf16(af[m][1], bfr[1], acc[m][p], 0, 0, 0);
      }
      __builtin_amdgcn_s_setprio(0);
      if (p == NF - 1)                                  // K-tile boundary: loads are
        asm volatile("s_waitcnt vmcnt(0)" ::: "memory");  // NF phases old -> cheap drain
      asm volatile("s_barrier" ::: "memory");
    }
  }

#pragma unroll
  for (int m = 0; m < 8; m++) {
#pragma unroll
    for (int n = 0; n < NF; n++) {
      int ccol = nb * BN + wn * (NF * 16) + n * 16 + l15;
      float bv = bias[ccol];
#pragma unroll
      for (int j = 0; j < 4; j++) {
        int r = mb * 256 + wm * 128 + m * 16 + l4 * 4 + j;
        float v = acc[m][n][j] + bv;
        if (OUT_BF16)
          ((unsigned short*)Cout)[(size_t)r * N + ccol] = f2b(v);
        else
          ((float*)Cout)[(size_t)r * N + ccol] = v;
      }
    }
  }
}

// ---------------- RoPE + head relayout + V transpose ----------------
// Q pre-scaled by (1/sqrt(64)) * log2(e) so attention can use exp2 directly.
__global__ __launch_bounds__(256)
void k_rope(const unsigned short* __restrict__ qkv, const float* __restrict__ rope,
            unsigned short* __restrict__ Qs, unsigned short* __restrict__ Ks,
            unsigned short* __restrict__ Vt) {
  __shared__ unsigned short vt_l[64][72];  // 16B-aligned rows (144B stride)
  const float QS = 0.125f * 1.44269504f;
  int bid = blockIdx.x;
  int tb = bid & 31, h = (bid >> 5) & 15, b = bid >> 9;
  int tid = threadIdx.x;
#pragma unroll
  for (int r = 0; r < 2; r++) {
    int e = (r * 256 + tid) * 8;
    int tl = e >> 6, d = e & 63;
    int t = tb * 64 + tl;
    const unsigned short* rowp = qkv + (size_t)(b * Tt + t) * 3072 + h * 64 + d;
    short8 qv = *reinterpret_cast<const short8*>(rowp);
    short8 kv = *reinterpret_cast<const short8*>(rowp + 1024);
    short8 vv = *reinterpret_cast<const short8*>(rowp + 2048);
    short8 qo, ko;
#pragma unroll
    for (int p = 0; p < 4; p++) {
      int j = (d >> 1) + p;
      float4 rv = *reinterpret_cast<const float4*>(rope + ((size_t)t * 32 + j) * 4);
      // rv = (cos, -sin, sin, cos)
      float xq = b2f(qv[2 * p]), yq = b2f(qv[2 * p + 1]);
      float xk = b2f(kv[2 * p]), yk = b2f(kv[2 * p + 1]);
      qo[2 * p]     = (short)f2b((xq * rv.x + yq * rv.y) * QS);
      qo[2 * p + 1] = (short)f2b((xq * rv.z + yq * rv.w) * QS);
      ko[2 * p]     = (short)f2b(xk * rv.x + yk * rv.y);
      ko[2 * p + 1] = (short)f2b(xk * rv.z + yk * rv.w);
    }
    size_t qdst = ((size_t)(b * 16 + h) * Tt + t) * 64 + d;
    *reinterpret_cast<short8*>(Qs + qdst) = qo;
    *reinterpret_cast<short8*>(Ks + qdst) = ko;
#pragma unroll
    for (int i2 = 0; i2 < 8; i2++) vt_l[d + i2][tl] = (unsigned short)vv[i2];
  }
  __syncthreads();
#pragma unroll
  for (int r = 0; r < 2; r++) {
    int e = (r * 256 + tid) * 8;
    int dl = e >> 6, tl = e & 63;
    short8 o = *reinterpret_cast<const short8*>(&vt_l[dl][tl]);
    *reinterpret_cast<short8*>(Vt + ((size_t)(b * 16 + h) * 64 + dl) * Tt + tb * 64 + tl) = o;
  }
}

__device__ __forceinline__ float tmax16(const f32x16& v) {
  float a0 = fmaxf(v[0], v[1]),   a1 = fmaxf(v[2], v[3]);
  float a2 = fmaxf(v[4], v[5]),   a3 = fmaxf(v[6], v[7]);
  float a4 = fmaxf(v[8], v[9]),   a5 = fmaxf(v[10], v[11]);
  float a6 = fmaxf(v[12], v[13]), a7 = fmaxf(v[14], v[15]);
  float b0 = fmaxf(a0, a1), b1 = fmaxf(a2, a3), b2 = fmaxf(a4, a5), b3 = fmaxf(a6, a7);
  return fmaxf(fmaxf(b0, b1), fmaxf(b2, b3));
}

// ---------------- causal flash attention: 32x32 swapped-QK^T, reg-resident P ------
template <bool DIAG>
__device__ __forceinline__ void attn_tile128(
    const unsigned short* Kl, const unsigned short* Vl,
    int w, int l31, int hi, const short8 qf[4],
    float& m_run, float& l_run, f32x16 oacc[2]) {
  const int ktmax = DIAG ? w : 3;
  f32x16 s[4];
#pragma unroll
  for (int kt = 0; kt < 4; kt++) {
    if (kt > ktmax) continue;          // wave-uniform
    f32x16 acc = {};
    int rk = kt * 32 + l31;
    int sw = (rk & 7) << 4;
    const unsigned short* krow = Kl + rk * 64;
#pragma unroll
    for (int kk = 0; kk < 4; kk++) {
      short8 kf = *reinterpret_cast<const short8*>(krow + (((kk * 32 + hi * 16) ^ sw) >> 1));
      acc = __builtin_amdgcn_mfma_f32_32x32x16_bf16(kf, qf[kk], acc, 0, 0, 0);
    }
    if (DIAG && kt == w) {
#pragma unroll
      for (int r = 0; r < 16; r++) {
        int e = (r & 3) + 8 * (r >> 2) + 4 * hi;   // key offset within 32-tile
        if (e > l31) acc[r] = -1e30f;              // q offset = l31
      }
    }
    s[kt] = acc;
  }
  float km[4];
#pragma unroll
  for (int kt = 0; kt < 4; kt++) km[kt] = (kt <= ktmax) ? tmax16(s[kt]) : -1e30f;
  float mx = fmaxf(fmaxf(km[0], km[1]), fmaxf(km[2], km[3]));
  mx = fmaxf(mx, __shfl_xor(mx, 32));
  float nm = fmaxf(m_run, mx);
  float fsc = __builtin_amdgcn_exp2f(m_run - nm);
  m_run = nm;
#pragma unroll
  for (int dt = 0; dt < 2; dt++)
#pragma unroll
    for (int r = 0; r < 16; r++) oacc[dt][r] *= fsc;

  float kps[4] = {0.f, 0.f, 0.f, 0.f};
#pragma unroll
  for (int kt = 0; kt < 4; kt++) {
    if (kt > ktmax) continue;
    float p[16];
#pragma unroll
    for (int r = 0; r < 16; r++) p[r] = __builtin_amdgcn_exp2f(s[kt][r] - nm);
    float s0 = (p[0] + p[1]) + (p[2] + p[3]);
    float s1 = (p[4] + p[5]) + (p[6] + p[7]);
    float s2 = (p[8] + p[9]) + (p[10] + p[11]);
    float s3 = (p[12] + p[13]) + (p[14] + p[15]);
    kps[kt] = (s0 + s1) + (s2 + s3);
    unsigned P[8];
#pragma unroll
    for (int i = 0; i < 8; i++) {
      unsigned lo = (__builtin_bit_cast(unsigned, p[2 * i]) + 0x8000u) >> 16;
      unsigned h2 = (__builtin_bit_cast(unsigned, p[2 * i + 1]) + 0x8000u) & 0xffff0000u;
      P[i] = lo | h2;
    }
    // partner-half exchange (lane ^ 32)
    unsigned Y0 = (unsigned)__shfl_xor((int)(hi ? P[0] : P[2]), 32);
    unsigned Y1 = (unsigned)__shfl_xor((int)(hi ? P[1] : P[3]), 32);
    unsigned Y2 = (unsigned)__shfl_xor((int)(hi ? P[4] : P[6]), 32);
    unsigned Y3 = (unsigned)__shfl_xor((int)(hi ? P[5] : P[7]), 32);
    u32x4 c0 = hi ? u32x4{Y0, Y1, P[2], P[3]} : u32x4{P[0], P[1], Y0, Y1};
    u32x4 c1 = hi ? u32x4{Y2, Y3, P[6], P[7]} : u32x4{P[4], P[5], Y2, Y3};
    short8 pf0 = __builtin_bit_cast(short8, c0);
    short8 pf1 = __builtin_bit_cast(short8, c1);
#pragma unroll
    for (int dt = 0; dt < 2; dt++) {
      int d = dt * 32 + l31;
      int sv = (d & 15) << 4;
      const unsigned short* vrow = Vl + d * 128;   // 256B V rows
      short8 vf0 = *reinterpret_cast<const short8*>(vrow + (((kt * 64 + hi * 16) ^ sv) >> 1));
      short8 vf1 = *reinterpret_cast<const short8*>(vrow + (((kt * 64 + 32 + hi * 16) ^ sv) >> 1));
      oacc[dt] = __builtin_amdgcn_mfma_f32_32x32x16_bf16(vf0, pf0, oacc[dt], 0, 0, 0);
      oacc[dt] = __builtin_amdgcn_mfma_f32_32x32x16_bf16(vf1, pf1, oacc[dt], 0, 0, 0);
    }
  }
  float psum = (kps[0] + kps[1]) + (kps[2] + kps[3]);
  psum += __shfl_xor(psum, 32);
  l_run = l_run * fsc + psum;
}

__global__ __launch_bounds__(256)
void k_attn(const unsigned short* __restrict__ Qs, const unsigned short* __restrict__ Ks,
            const unsigned short* __restrict__ Vt, unsigned short* __restrict__ Y) {
  __shared__ unsigned short lds[32768];  // 64KB: K0|K1 (16K shorts) + V0|V1 (16K)
  int tid = threadIdx.x, lane = tid & 63, w = tid >> 6;
  // Complementary-pair dispatch: blocks s and s+256 share (bh,j) and get
  // qb = 15-j and qb = j -> per-CU work sums to 17 units under round-robin.
  int s = blockIdx.x;                  // 0..511
  int half = s >> 8;
  int p = s & 255;
  int bh = p >> 3;                     // 0..31
  int j = p & 7;
  int qb = half ? j : 15 - j;
  int b = bh >> 4, h = bh & 15;
  int l31 = lane & 31, hi = lane >> 5;
  int qw0 = qb * 128 + w * 32;
  const unsigned short* Qb = Qs + (size_t)bh * Tt * 64;
  const unsigned short* Kb = Ks + (size_t)bh * Tt * 64;
  const unsigned short* Vb = Vt + (size_t)bh * 64 * Tt;

  auto stage = [&](int buf, int kv0) {
    unsigned short* Kbuf = lds + buf * 8192;
    unsigned short* Vbuf = lds + 16384 + buf * 8192;
    int krow = lane >> 3;
    int kcolb = ((lane & 7) * 16) ^ ((krow & 7) << 4);
#pragma unroll
    for (int cc = 0; cc < 4; cc++) {
      int c = w + cc * 4;                // wave-uniform chunk 0..15
      const unsigned short* gk = Kb + (size_t)(kv0 + c * 8 + krow) * 64 + (kcolb >> 1);
      __builtin_amdgcn_global_load_lds((const __attribute__((address_space(1))) void*)gk,
          (__attribute__((address_space(3))) void*)(Kbuf + c * 512), 16, 0, 0);
      int vr = c * 4 + (lane >> 4);
      int vcolb = ((lane & 15) * 16) ^ ((vr & 15) << 4);
      const unsigned short* gv = Vb + (size_t)vr * Tt + kv0 + (vcolb >> 1);
      __builtin_amdgcn_global_load_lds((const __attribute__((address_space(1))) void*)gv,
          (__attribute__((address_space(3))) void*)(Vbuf + c * 512), 16, 0, 0);
    }
  };

  short8 qf[4];
#pragma unroll
  for (int kk = 0; kk < 4; kk++)
    qf[kk] = *reinterpret_cast<const short8*>(Qb + (size_t)(qw0 + l31) * 64 + kk * 16 + hi * 8);

  float m_run = -1e30f, l_run = 0.f;
  f32x16 oacc[2] = {};
  const int nt = qb + 1;

  stage(0, 0);
  __syncthreads();
  int cur = 0;
  for (int it = 0; it < nt - 1; ++it) {
    stage(cur ^ 1, (it + 1) * 128);      // async prefetch next tile
    attn_tile128<false>(lds + cur * 8192, lds + 16384 + cur * 8192,
                        w, l31, hi, qf, m_run, l_run, oacc);
    __syncthreads();                     // drains vmcnt (stage) + lgkm
    cur ^= 1;
  }
  attn_tile128<true>(lds + cur * 8192, lds + 16384 + cur * 8192,
                     w, l31, hi, qf, m_run, l_run, oacc);

  float inv = 1.0f / l_run;
  int t = qw0 + l31;
  unsigned short* yrow = Y + ((size_t)b * Tt + t) * Cc + h * 64;
#pragma unroll
  for (int dt = 0; dt < 2; dt++)
#pragma unroll
    for (int q4 = 0; q4 < 4; q4++) {
      short4b o;
#pragma unroll
      for (int jj = 0; jj < 4; jj++) o[jj] = (short)f2b(oacc[dt][q4 * 4 + jj] * inv);
      *reinterpret_cast<short4b*>(yrow + dt * 32 + q4 * 8 + hi * 4) = o;
    }
}

extern "C" void kernel_launch(void* const* d_in, const int* in_sizes, int n_in,
                              void* d_out, int out_size, void* d_ws, size_t ws_size,
                              hipStream_t stream) {
  (void)in_sizes; (void)n_in; (void)out_size; (void)ws_size;
  const float* x      = (const float*)d_in[0];
  const float* W_attn = (const float*)d_in[1];
  const float* b_attn = (const float*)d_in[2];
  const float* W_proj = (const float*)d_in[3];
  const float* b_proj = (const float*)d_in[4];
  const float* rope   = (const float*)d_in[5];
  float* out = (float*)d_out;

  char* ws = (char*)d_ws;
  unsigned short* xb  = (unsigned short*)(ws);                     // 8 MB
  unsigned short* WaT = (unsigned short*)(ws + (8u << 20));        // 6 MB
  unsigned short* WpT = (unsigned short*)(ws + (14u << 20));       // 2 MB
  unsigned short* qkv = (unsigned short*)(ws + (16u << 20));       // 24 MB
  unsigned short* Qs  = (unsigned short*)(ws + (40u << 20));       // 8 MB
  unsigned short* Ks  = (unsigned short*)(ws + (48u << 20));       // 8 MB
  unsigned short* Vt  = (unsigned short*)(ws + (56u << 20));       // 8 MB
  unsigned short* Yb  = (unsigned short*)(ws + (64u << 20));       // 8 MB  (total 72 MB)

  constexpr int LDS_QKV  = (256 + 192) * 64 * 2 * 2;  // 114688 B
  constexpr int LDS_PROJ = (256 + 128) * 64 * 2 * 2;  //  98304 B
  (void)hipFuncSetAttribute(reinterpret_cast<const void*>(&k_gemm8<3, 1>),
                            hipFuncAttributeMaxDynamicSharedMemorySize, LDS_QKV);
  (void)hipFuncSetAttribute(reinterpret_cast<const void*>(&k_gemm8<2, 0>),
                            hipFuncAttributeMaxDynamicSharedMemorySize, LDS_PROJ);

  k_cast<<<2048, 256, 0, stream>>>(x, xb, BT * Cc);
  k_tcast<<<dim3(N1 / 32, Cc / 32), 256, 0, stream>>>(W_attn, WaT, Cc, N1);
  k_tcast<<<dim3(Cc / 32, Cc / 32), 256, 0, stream>>>(W_proj, WpT, Cc, Cc);
  k_gemm8<3, 1><<<dim3(N1 / 192, BT / 256), 512, LDS_QKV, stream>>>(xb, WaT, b_attn, qkv, BT, N1, Cc);
  k_rope<<<Bb * Hh * (Tt / 64), 256, 0, stream>>>(qkv, rope, Qs, Ks, Vt);
  k_attn<<<Bb * Hh * (Tt / 128), 256, 0, stream>>>(Qs, Ks, Vt, Yb);
  k_gemm8<2, 0><<<dim3(Cc / 128, BT / 256), 512, LDS_PROJ, stream>>>(Yb, WpT, b_proj, out, BT, Cc, Cc);
}